// Round 1
// baseline (675.423 us; speedup 1.0000x reference)
//
#include <hip/hip_runtime.h>
#include <hip/hip_bf16.h>

// ---- problem constants ----
#define DB   2
#define DS   2048
#define DH   2048
#define DNH  32
#define DKVH 8
#define DHD  64
#define DM   4096    // B*S
#define DNQKV 3072   // NH*HD + 2*KVH*HD

typedef __attribute__((ext_vector_type(8))) short bf16x8;
typedef __attribute__((ext_vector_type(4))) float f32x4;
typedef __attribute__((ext_vector_type(8))) unsigned short us8;

__device__ __forceinline__ float b2f(unsigned short u) {
  unsigned int x = ((unsigned int)u) << 16;
  return __builtin_bit_cast(float, x);
}
__device__ __forceinline__ unsigned short f2b(float f) {
  unsigned int u = __builtin_bit_cast(unsigned int, f);
  u += 0x7FFFu + ((u >> 16) & 1u);
  return (unsigned short)(u >> 16);
}
__device__ __forceinline__ void async_copy16(void* lds, const void* g) {
  __builtin_amdgcn_global_load_lds((const __attribute__((address_space(1))) void*)g,
                                   (__attribute__((address_space(3))) void*)lds,
                                   16, 0, 0);
}

// ---- dtype detector: decode Wq halfwords as bf16; fp32 data => wild exponents ----
__global__ void detect_mode(const unsigned short* __restrict__ w, int* __restrict__ flags) {
  int t = threadIdx.x;
  int trips = 0;
  for (int i = 0; i < 4; i++) {
    unsigned short u = w[t * 4 + i];
    int e = (u >> 7) & 0xFF;
    if (e >= 161 || (e <= 93 && e != 0)) trips++;
  }
  for (int off = 32; off > 0; off >>= 1) trips += __shfl_down(trips, off);
  if (t == 0) {
    flags[0] = (trips >= 8) ? 1 : 0;  // 1 = fp32 inputs/outputs, 0 = bf16
    flags[1] = 0;                     // constant "bf16 out" mode for internal GEMM
  }
}

// ---- X (fp32 or bf16) -> bf16 ----
__global__ __launch_bounds__(256) void convert_x(const void* __restrict__ xin,
                                                 unsigned short* __restrict__ xb,
                                                 const int* __restrict__ flags, int n) {
  int mode = flags[0];
  int i = (blockIdx.x * 256 + threadIdx.x) * 8;
  if (i >= n) return;
  if (mode) {
    const float* f = (const float*)xin;
    us8 o;
#pragma unroll
    for (int j = 0; j < 8; j++) o[j] = f2b(f[i + j]);
    *(us8*)&xb[i] = o;
  } else {
    *(us8*)&xb[i] = *(const us8*)((const unsigned short*)xin + i);
  }
}

// ---- W [R][C] (fp32 or bf16) -> bf16 W^T [C][R] ----
__global__ __launch_bounds__(256) void transpose_w(const void* __restrict__ win,
                                                   unsigned short* __restrict__ out,
                                                   const int* __restrict__ flags,
                                                   int R, int C) {
  __shared__ float tile[32][33];
  int mode = flags[0];
  int c0 = blockIdx.x * 32, r0 = blockIdx.y * 32;
  int tx = threadIdx.x & 31, ty = threadIdx.x >> 5;
  if (mode) {
    const float* f = (const float*)win;
    for (int i = ty; i < 32; i += 8) tile[i][tx] = f[(size_t)(r0 + i) * C + c0 + tx];
  } else {
    const unsigned short* bsrc = (const unsigned short*)win;
    for (int i = ty; i < 32; i += 8) tile[i][tx] = b2f(bsrc[(size_t)(r0 + i) * C + c0 + tx]);
  }
  __syncthreads();
  for (int i = ty; i < 32; i += 8) out[(size_t)(c0 + i) * R + r0 + tx] = f2b(tile[tx][i]);
}

// ---- GEMM: C[M,N] = A[M,K] * Bt[N,K]^T, bf16 in, bf16 or fp32 out ----
__global__ __launch_bounds__(256)
void gemm_bt(const unsigned short* __restrict__ A, const unsigned short* __restrict__ Bt,
             unsigned short* __restrict__ Cb, float* __restrict__ Cf,
             const int* __restrict__ outmode, int M, int N, int K) {
  __shared__ __align__(16) unsigned short lA[128 * 32];
  __shared__ __align__(16) unsigned short lB[128 * 32];
  int tid = threadIdx.x, lane = tid & 63, wave = tid >> 6;
  int wm = wave >> 1, wn = wave & 1;
  int quad = lane >> 4, l15 = lane & 15;
  size_t tm0 = (size_t)blockIdx.y * 128, tn0 = (size_t)blockIdx.x * 128;

  f32x4 zero4 = {0.f, 0.f, 0.f, 0.f};
  f32x4 acc[4][4];
#pragma unroll
  for (int mi = 0; mi < 4; mi++)
#pragma unroll
    for (int ni = 0; ni < 4; ni++) acc[mi][ni] = zero4;

  int nk = K >> 5;
  for (int kt = 0; kt < nk; kt++) {
    __syncthreads();
#pragma unroll
    for (int i = 0; i < 2; i++) {
      int c = tid + 256 * i;
      int r = c >> 2, cb = (c & 3) * 8;
      async_copy16(&lA[c * 8], A + (tm0 + r) * K + kt * 32 + cb);
      async_copy16(&lB[c * 8], Bt + (tn0 + r) * K + kt * 32 + cb);
    }
    __syncthreads();
    bf16x8 af[4], bfr[4];
#pragma unroll
    for (int mi = 0; mi < 4; mi++)
      af[mi] = *(const bf16x8*)&lA[(wm * 64 + mi * 16 + l15) * 32 + quad * 8];
#pragma unroll
    for (int ni = 0; ni < 4; ni++)
      bfr[ni] = *(const bf16x8*)&lB[(wn * 64 + ni * 16 + l15) * 32 + quad * 8];
#pragma unroll
    for (int mi = 0; mi < 4; mi++)
#pragma unroll
      for (int ni = 0; ni < 4; ni++)
        acc[mi][ni] = __builtin_amdgcn_mfma_f32_16x16x32_bf16(af[mi], bfr[ni], acc[mi][ni], 0, 0, 0);
  }
  int mode = *outmode;
#pragma unroll
  for (int mi = 0; mi < 4; mi++)
#pragma unroll
    for (int ni = 0; ni < 4; ni++)
#pragma unroll
      for (int r = 0; r < 4; r++) {
        size_t gr = tm0 + wm * 64 + mi * 16 + quad * 4 + r;
        size_t gc = tn0 + wn * 64 + ni * 16 + l15;
        float v = acc[mi][ni][r];
        if (mode) Cf[gr * N + gc] = v;
        else      Cb[gr * N + gc] = f2b(v);
      }
}

// ---- RoPE on Q,K from c1 [4096,3072] into head-major q/k ----
__global__ __launch_bounds__(256) void rope_qk(const unsigned short* __restrict__ c1,
                                               const int* __restrict__ pos_ids,
                                               unsigned short* __restrict__ qws,
                                               unsigned short* __restrict__ kws) {
  int idx = blockIdx.x * 256 + threadIdx.x;      // < 4096*40*32
  int row = idx / 1280;
  int rem = idx - row * 1280;
  int head = rem >> 5, d = rem & 31;
  int b = row >> 11, s = row & 2047;
  float t = (float)pos_ids[row];
  // inv_freq = 10000^(-d/32) = exp(-d * ln(10000)/32)
  float invf = __expf(-(float)d * (9.210340371976184f / 32.0f));
  float ang = t * invf;
  float sn, cs;
  __sincosf(ang, &sn, &cs);
  size_t col;
  unsigned short* dst;
  if (head < 32) {
    col = (size_t)head * 64 + d;
    dst = qws + ((size_t)(b * DNH + head) * DS + s) * DHD + d;
  } else {
    int kh = head - 32;
    col = 2048 + (size_t)kh * 64 + d;
    dst = kws + ((size_t)(b * DKVH + kh) * DS + s) * DHD + d;
  }
  float x1 = b2f(c1[(size_t)row * DNQKV + col]);
  float x2 = b2f(c1[(size_t)row * DNQKV + col + 32]);
  dst[0]  = f2b(x1 * cs - x2 * sn);
  dst[32] = f2b(x2 * cs + x1 * sn);
}

// ---- V copy from c1 into head-major v ----
__global__ __launch_bounds__(256) void copy_v(const unsigned short* __restrict__ c1,
                                              unsigned short* __restrict__ vws) {
  int idx = blockIdx.x * 256 + threadIdx.x;   // < 4096*64
  int row = idx >> 6, u = idx & 63;
  int b = row >> 11, s = row & 2047;
  int kh = u >> 3, d0 = (u & 7) * 8;
  us8 vv = *(const us8*)&c1[(size_t)row * DNQKV + 2560 + kh * 64 + d0];
  *(us8*)&vws[((size_t)(b * DKVH + kh) * DS + s) * DHD + d0] = vv;
}

// ---- causal GQA flash attention ----
__global__ __launch_bounds__(256)
void flash_attn(const unsigned short* __restrict__ q, const unsigned short* __restrict__ k,
                const unsigned short* __restrict__ v, unsigned short* __restrict__ ctx) {
  __shared__ __align__(16) unsigned short lK[64 * 64];
  __shared__ __align__(16) unsigned short lVt[64 * 64];
  __shared__ __align__(16) unsigned short lP[4 * 16 * 64];
  int tid = threadIdx.x, lane = tid & 63, wave = tid >> 6;
  int quad = lane >> 4, l15 = lane & 15;
  int q0 = blockIdx.x * 64;
  int bh = blockIdx.y;
  int b = bh >> 5, h = bh & 31;
  int kvh = h >> 2;
  const unsigned short* qb = q + (size_t)(b * DNH + h) * DS * DHD;
  const unsigned short* kb = k + (size_t)(b * DKVH + kvh) * DS * DHD;
  const unsigned short* vb = v + (size_t)(b * DKVH + kvh) * DS * DHD;

  bf16x8 aq0, aq1;
  {
    const unsigned short* qp = qb + (size_t)(q0 + wave * 16 + l15) * DHD + quad * 8;
    aq0 = *(const bf16x8*)qp;
    aq1 = *(const bf16x8*)(qp + 32);
  }
  f32x4 zero4 = {0.f, 0.f, 0.f, 0.f};
  f32x4 oacc[4];
#pragma unroll
  for (int dj = 0; dj < 4; dj++) oacc[dj] = zero4;
  float mrow[4] = {-1e30f, -1e30f, -1e30f, -1e30f};
  float lrow[4] = {0.f, 0.f, 0.f, 0.f};

  int ntiles = (q0 >> 6) + 1;
  for (int t = 0; t < ntiles; t++) {
    int kv0 = t * 64;
    __syncthreads();
#pragma unroll
    for (int i = 0; i < 2; i++) {
      int c = tid + 256 * i;
      int kr = c >> 3, cb = (c & 7) * 8;
      async_copy16(&lK[c * 8], kb + (size_t)(kv0 + kr) * DHD + cb);
    }
#pragma unroll
    for (int i = 0; i < 2; i++) {
      int c = tid + 256 * i;
      int kr = c >> 3, d0 = (c & 7) * 8;
      us8 vv = *(const us8*)(vb + (size_t)(kv0 + kr) * DHD + d0);
#pragma unroll
      for (int j = 0; j < 8; j++) lVt[(d0 + j) * 64 + kr] = vv[j];
    }
    __syncthreads();

    f32x4 sacc[4];
#pragma unroll
    for (int nj = 0; nj < 4; nj++) {
      sacc[nj] = zero4;
      bf16x8 bk0 = *(const bf16x8*)&lK[(nj * 16 + l15) * 64 + quad * 8];
      bf16x8 bk1 = *(const bf16x8*)&lK[(nj * 16 + l15) * 64 + 32 + quad * 8];
      sacc[nj] = __builtin_amdgcn_mfma_f32_16x16x32_bf16(aq0, bk0, sacc[nj], 0, 0, 0);
      sacc[nj] = __builtin_amdgcn_mfma_f32_16x16x32_bf16(aq1, bk1, sacc[nj], 0, 0, 0);
    }

    bool lastt = (t == ntiles - 1);
    float z[4][4], tm[4];
#pragma unroll
    for (int r = 0; r < 4; r++) tm[r] = -1e30f;
#pragma unroll
    for (int nj = 0; nj < 4; nj++)
#pragma unroll
      for (int r = 0; r < 4; r++) {
        float zz = sacc[nj][r] * 0.125f;
        if (lastt) {
          int kvcol = kv0 + nj * 16 + l15;
          int qr = q0 + wave * 16 + quad * 4 + r;
          if (kvcol > qr) zz = -1e30f;
        }
        z[nj][r] = zz;
        tm[r] = fmaxf(tm[r], zz);
      }
    float alpha[4], rs[4];
#pragma unroll
    for (int r = 0; r < 4; r++) {
      tm[r] = fmaxf(tm[r], __shfl_xor(tm[r], 1));
      tm[r] = fmaxf(tm[r], __shfl_xor(tm[r], 2));
      tm[r] = fmaxf(tm[r], __shfl_xor(tm[r], 4));
      tm[r] = fmaxf(tm[r], __shfl_xor(tm[r], 8));
      float mn = fmaxf(mrow[r], tm[r]);
      alpha[r] = __expf(mrow[r] - mn);
      mrow[r] = mn;
      rs[r] = 0.f;
    }
#pragma unroll
    for (int nj = 0; nj < 4; nj++)
#pragma unroll
      for (int r = 0; r < 4; r++) {
        float p = __expf(z[nj][r] - mrow[r]);
        z[nj][r] = p;
        rs[r] += p;
      }
#pragma unroll
    for (int r = 0; r < 4; r++) {
      rs[r] += __shfl_xor(rs[r], 1);
      rs[r] += __shfl_xor(rs[r], 2);
      rs[r] += __shfl_xor(rs[r], 4);
      rs[r] += __shfl_xor(rs[r], 8);
      lrow[r] = lrow[r] * alpha[r] + rs[r];
    }
    // P (C-layout) -> LDS -> A-layout frags (wave-private)
    unsigned short* lPw = lP + wave * 1024;
#pragma unroll
    for (int nj = 0; nj < 4; nj++)
#pragma unroll
      for (int r = 0; r < 4; r++)
        lPw[(quad * 4 + r) * 64 + nj * 16 + l15] = f2b(z[nj][r]);
    bf16x8 ap0 = *(const bf16x8*)&lPw[l15 * 64 + quad * 8];
    bf16x8 ap1 = *(const bf16x8*)&lPw[l15 * 64 + 32 + quad * 8];
#pragma unroll
    for (int dj = 0; dj < 4; dj++) {
#pragma unroll
      for (int r = 0; r < 4; r++) oacc[dj][r] *= alpha[r];
      bf16x8 bv0 = *(const bf16x8*)&lVt[(dj * 16 + l15) * 64 + quad * 8];
      bf16x8 bv1 = *(const bf16x8*)&lVt[(dj * 16 + l15) * 64 + 32 + quad * 8];
      oacc[dj] = __builtin_amdgcn_mfma_f32_16x16x32_bf16(ap0, bv0, oacc[dj], 0, 0, 0);
      oacc[dj] = __builtin_amdgcn_mfma_f32_16x16x32_bf16(ap1, bv1, oacc[dj], 0, 0, 0);
    }
  }
  float inv[4];
#pragma unroll
  for (int r = 0; r < 4; r++) inv[r] = 1.0f / lrow[r];
  size_t orow0 = ((size_t)b * DS + q0 + wave * 16) * (DNH * DHD) + (size_t)h * DHD;
#pragma unroll
  for (int dj = 0; dj < 4; dj++)
#pragma unroll
    for (int r = 0; r < 4; r++)
      ctx[orow0 + (size_t)(quad * 4 + r) * (DNH * DHD) + dj * 16 + l15] =
          f2b(oacc[dj][r] * inv[r]);
}

extern "C" void kernel_launch(void* const* d_in, const int* in_sizes, int n_in,
                              void* d_out, int out_size, void* d_ws, size_t ws_size,
                              hipStream_t stream) {
  (void)in_sizes; (void)n_in; (void)out_size; (void)ws_size;
  const void* hs = d_in[0];
  const int* pos = (const int*)d_in[2];
  const void* wq = d_in[3];
  const void* wk = d_in[4];
  const void* wv = d_in[5];
  const void* wo = d_in[6];

  char* ws = (char*)d_ws;
  size_t off = 0;
  auto take = [&](size_t bytes) -> char* {
    char* p = ws + off;
    off += (bytes + 255) & ~(size_t)255;
    return p;
  };
  int* flags            = (int*)take(256);
  unsigned short* xb    = (unsigned short*)take((size_t)DM * DH * 2);
  unsigned short* wtqkv = (unsigned short*)take((size_t)DNQKV * DH * 2);
  unsigned short* wto   = (unsigned short*)take((size_t)DH * DH * 2);
  unsigned short* c1    = (unsigned short*)take((size_t)DM * DNQKV * 2);
  unsigned short* qws   = (unsigned short*)take((size_t)DB * DNH * DS * DHD * 2);
  unsigned short* kws   = (unsigned short*)take((size_t)DB * DKVH * DS * DHD * 2);
  unsigned short* vws   = (unsigned short*)take((size_t)DB * DKVH * DS * DHD * 2);
  unsigned short* ctx   = (unsigned short*)take((size_t)DM * DNH * DHD * 2);

  detect_mode<<<1, 64, 0, stream>>>((const unsigned short*)wq, flags);
  convert_x<<<DM * DH / 8 / 256, 256, 0, stream>>>(hs, xb, flags, DM * DH);
  transpose_w<<<dim3(64, 64), 256, 0, stream>>>(wq, wtqkv, flags, 2048, 2048);
  transpose_w<<<dim3(16, 64), 256, 0, stream>>>(wk, wtqkv + (size_t)2048 * 2048, flags, 2048, 512);
  transpose_w<<<dim3(16, 64), 256, 0, stream>>>(wv, wtqkv + (size_t)2560 * 2048, flags, 2048, 512);
  transpose_w<<<dim3(64, 64), 256, 0, stream>>>(wo, wto, flags, 2048, 2048);

  gemm_bt<<<dim3(DNQKV / 128, DM / 128), 256, 0, stream>>>(
      xb, wtqkv, c1, (float*)nullptr, flags + 1, DM, DNQKV, DH);

  rope_qk<<<DM * 40 * 32 / 256, 256, 0, stream>>>(c1, pos, qws, kws);
  copy_v<<<DM * 64 / 256, 256, 0, stream>>>(c1, vws);

  flash_attn<<<dim3(DS / 64, DB * DNH), 256, 0, stream>>>(qws, kws, vws, ctx);

  gemm_bt<<<dim3(DH / 128, DM / 128), 256, 0, stream>>>(
      ctx, wto, (unsigned short*)d_out, (float*)d_out, flags, DM, DH, DH);
}

// Round 2
// 373.741 us; speedup vs baseline: 1.8072x; 1.8072x over previous
//
#include <hip/hip_runtime.h>
#include <hip/hip_bf16.h>

// ---- problem constants ----
#define DB   2
#define DS   2048
#define DH   2048
#define DNH  32
#define DKVH 8
#define DHD  64
#define DM   4096    // B*S
#define DNQKV 3072   // NH*HD + 2*KVH*HD

typedef __attribute__((ext_vector_type(8))) short bf16x8;
typedef __attribute__((ext_vector_type(4))) float f32x4;
typedef __attribute__((ext_vector_type(8))) unsigned short us8;
typedef __attribute__((ext_vector_type(4))) unsigned short us4;

__device__ __forceinline__ float b2f(unsigned short u) {
  unsigned int x = ((unsigned int)u) << 16;
  return __builtin_bit_cast(float, x);
}
// cheap round-half-up bf16 (1 ulp from RNE, 2 VALU ops)
__device__ __forceinline__ unsigned short f2b(float f) {
  unsigned int u = __builtin_bit_cast(unsigned int, f);
  return (unsigned short)((u + 0x8000u) >> 16);
}
__device__ __forceinline__ void async_copy16(void* lds, const void* g) {
  __builtin_amdgcn_global_load_lds((const __attribute__((address_space(1))) void*)g,
                                   (__attribute__((address_space(3))) void*)lds,
                                   16, 0, 0);
}

// ---- dtype detector: decode Wq halfwords as bf16; fp32 data => wild exponents ----
__global__ void detect_mode(const unsigned short* __restrict__ w, int* __restrict__ flags) {
  int t = threadIdx.x;
  int trips = 0;
  for (int i = 0; i < 4; i++) {
    unsigned short u = w[t * 4 + i];
    int e = (u >> 7) & 0xFF;
    if (e >= 161 || (e <= 93 && e != 0)) trips++;
  }
  for (int off = 32; off > 0; off >>= 1) trips += __shfl_down(trips, off);
  if (t == 0) {
    flags[0] = (trips >= 8) ? 1 : 0;  // 1 = fp32 inputs/outputs, 0 = bf16
    flags[1] = 0;                     // constant "bf16 out" mode for internal GEMM
  }
}

// ---- X (fp32 or bf16) -> bf16 ----
__global__ __launch_bounds__(256) void convert_x(const void* __restrict__ xin,
                                                 unsigned short* __restrict__ xb,
                                                 const int* __restrict__ flags, int n) {
  int mode = flags[0];
  int i = (blockIdx.x * 256 + threadIdx.x) * 8;
  if (i >= n) return;
  if (mode) {
    const float* f = (const float*)xin;
    us8 o;
#pragma unroll
    for (int j = 0; j < 8; j++) o[j] = f2b(f[i + j]);
    *(us8*)&xb[i] = o;
  } else {
    *(us8*)&xb[i] = *(const us8*)((const unsigned short*)xin + i);
  }
}

// ---- W [R][C] (fp32 or bf16) -> bf16 W^T [C][R] ----
__global__ __launch_bounds__(256) void transpose_w(const void* __restrict__ win,
                                                   unsigned short* __restrict__ out,
                                                   const int* __restrict__ flags,
                                                   int R, int C) {
  __shared__ float tile[32][33];
  int mode = flags[0];
  int c0 = blockIdx.x * 32, r0 = blockIdx.y * 32;
  int tx = threadIdx.x & 31, ty = threadIdx.x >> 5;
  if (mode) {
    const float* f = (const float*)win;
    for (int i = ty; i < 32; i += 8) tile[i][tx] = f[(size_t)(r0 + i) * C + c0 + tx];
  } else {
    const unsigned short* bsrc = (const unsigned short*)win;
    for (int i = ty; i < 32; i += 8) tile[i][tx] = b2f(bsrc[(size_t)(r0 + i) * C + c0 + tx]);
  }
  __syncthreads();
  for (int i = ty; i < 32; i += 8) out[(size_t)(c0 + i) * R + r0 + tx] = f2b(tile[tx][i]);
}

// ---- GEMM: C[M,N] = A[M,K] * Bt[N,K]^T, bf16 in, bf16 or fp32 out ----
__global__ __launch_bounds__(256)
void gemm_bt(const unsigned short* __restrict__ A, const unsigned short* __restrict__ Bt,
             unsigned short* __restrict__ Cb, float* __restrict__ Cf,
             const int* __restrict__ outmode, int M, int N, int K) {
  __shared__ __align__(16) unsigned short lA[128 * 32];
  __shared__ __align__(16) unsigned short lB[128 * 32];
  int tid = threadIdx.x, lane = tid & 63, wave = tid >> 6;
  int wm = wave >> 1, wn = wave & 1;
  int quad = lane >> 4, l15 = lane & 15;
  size_t tm0 = (size_t)blockIdx.y * 128, tn0 = (size_t)blockIdx.x * 128;

  f32x4 zero4 = {0.f, 0.f, 0.f, 0.f};
  f32x4 acc[4][4];
#pragma unroll
  for (int mi = 0; mi < 4; mi++)
#pragma unroll
    for (int ni = 0; ni < 4; ni++) acc[mi][ni] = zero4;

  int nk = K >> 5;
  for (int kt = 0; kt < nk; kt++) {
    __syncthreads();
#pragma unroll
    for (int i = 0; i < 2; i++) {
      int c = tid + 256 * i;
      int r = c >> 2, cb = (c & 3) * 8;
      async_copy16(&lA[c * 8], A + (tm0 + r) * K + kt * 32 + cb);
      async_copy16(&lB[c * 8], Bt + (tn0 + r) * K + kt * 32 + cb);
    }
    __syncthreads();
    bf16x8 af[4], bfr[4];
#pragma unroll
    for (int mi = 0; mi < 4; mi++)
      af[mi] = *(const bf16x8*)&lA[(wm * 64 + mi * 16 + l15) * 32 + quad * 8];
#pragma unroll
    for (int ni = 0; ni < 4; ni++)
      bfr[ni] = *(const bf16x8*)&lB[(wn * 64 + ni * 16 + l15) * 32 + quad * 8];
#pragma unroll
    for (int mi = 0; mi < 4; mi++)
#pragma unroll
      for (int ni = 0; ni < 4; ni++)
        acc[mi][ni] = __builtin_amdgcn_mfma_f32_16x16x32_bf16(af[mi], bfr[ni], acc[mi][ni], 0, 0, 0);
  }
  int mode = *outmode;
#pragma unroll
  for (int mi = 0; mi < 4; mi++)
#pragma unroll
    for (int ni = 0; ni < 4; ni++)
#pragma unroll
      for (int r = 0; r < 4; r++) {
        size_t gr = tm0 + wm * 64 + mi * 16 + quad * 4 + r;
        size_t gc = tn0 + wn * 64 + ni * 16 + l15;
        float v = acc[mi][ni][r];
        if (mode) Cf[gr * N + gc] = v;
        else      Cb[gr * N + gc] = f2b(v);
      }
}

// ---- RoPE on Q,K from c1 [4096,3072] into head-major q/k ----
// Q additionally pre-scaled by SCALE*log2(e) so flash softmax runs in exp2 domain.
#define QSC 0.18033688011112042f   // (1/8) * 1.4426950408889634
__global__ __launch_bounds__(256) void rope_qk(const unsigned short* __restrict__ c1,
                                               const int* __restrict__ pos_ids,
                                               unsigned short* __restrict__ qws,
                                               unsigned short* __restrict__ kws) {
  int idx = blockIdx.x * 256 + threadIdx.x;      // < 4096*40*32
  int row = idx / 1280;
  int rem = idx - row * 1280;
  int head = rem >> 5, d = rem & 31;
  int b = row >> 11, s = row & 2047;
  float t = (float)pos_ids[row];
  float invf = __expf(-(float)d * (9.210340371976184f / 32.0f));
  float ang = t * invf;
  float sn, cs;
  __sincosf(ang, &sn, &cs);
  size_t col;
  unsigned short* dst;
  float sc;
  if (head < 32) {
    col = (size_t)head * 64 + d;
    dst = qws + ((size_t)(b * DNH + head) * DS + s) * DHD + d;
    sc = QSC;
  } else {
    int kh = head - 32;
    col = 2048 + (size_t)kh * 64 + d;
    dst = kws + ((size_t)(b * DKVH + kh) * DS + s) * DHD + d;
    sc = 1.0f;
  }
  float x1 = b2f(c1[(size_t)row * DNQKV + col]);
  float x2 = b2f(c1[(size_t)row * DNQKV + col + 32]);
  dst[0]  = f2b((x1 * cs - x2 * sn) * sc);
  dst[32] = f2b((x2 * cs + x1 * sn) * sc);
}

// ---- V from c1 -> global V^T  vt[b][kvh][d][s] ----
__global__ __launch_bounds__(256) void transpose_v(const unsigned short* __restrict__ c1,
                                                   unsigned short* __restrict__ vt) {
  __shared__ unsigned short tile[64 * 72];
  int s0 = blockIdx.x * 64;
  int bk = blockIdx.y;               // b*8+kvh
  int b = bk >> 3, kvh = bk & 7;
  const unsigned short* src = c1 + (size_t)(b * DS + s0) * DNQKV + 2560 + kvh * 64;
#pragma unroll
  for (int i = 0; i < 2; i++) {
    int c = threadIdx.x + 256 * i;
    int s = c >> 3, d0 = (c & 7) * 8;
    *(us8*)&tile[s * 72 + d0] = *(const us8*)(src + (size_t)s * DNQKV + d0);
  }
  __syncthreads();
  unsigned short* dst = vt + (size_t)bk * 64 * DS + s0;
#pragma unroll
  for (int i = 0; i < 2; i++) {
    int c = threadIdx.x + 256 * i;
    int d = c >> 3, sc = (c & 7) * 8;
    us8 o;
#pragma unroll
    for (int j = 0; j < 8; j++) o[j] = tile[(sc + j) * 72 + d];
    *(us8*)&dst[(size_t)d * DS + sc] = o;
  }
}

// ---- causal GQA flash attention (S^T form, paired q-tiles for uniform work) ----
// block x handles q-tiles {x, 31-x}: 33 KV-tiles each -> zero tail imbalance.
__global__ __launch_bounds__(256, 4)
void flash_attn(const unsigned short* __restrict__ q, const unsigned short* __restrict__ k,
                const unsigned short* __restrict__ vt, unsigned short* __restrict__ ctx) {
  __shared__ __align__(16) unsigned short lK0[64 * 32];  // K d 0..31
  __shared__ __align__(16) unsigned short lK1[64 * 32];  // K d 32..63
  __shared__ __align__(16) unsigned short lV0[64 * 32];  // V^T kv 0..31 (rows d)
  __shared__ __align__(16) unsigned short lV1[64 * 32];  // V^T kv 32..63
  __shared__ __align__(16) unsigned short lP[4 * 16 * 72];
  int tid = threadIdx.x, lane = tid & 63, wave = tid >> 6;
  int quad = lane >> 4, l15 = lane & 15;
  int bh = blockIdx.y, b = bh >> 5, h = bh & 31, kvh = h >> 2;
  const unsigned short* qb = q + (size_t)(b * DNH + h) * DS * DHD;
  const unsigned short* kb = k + (size_t)(b * DKVH + kvh) * DS * DHD;
  const unsigned short* vb = vt + (size_t)(b * DKVH + kvh) * DHD * DS;
  unsigned short* lPw = lP + wave * 16 * 72;
  int r4 = tid >> 2, c8 = (tid & 3) * 8;

  f32x4 zero4 = {0.f, 0.f, 0.f, 0.f};
  for (int ph = 0; ph < 2; ph++) {
    int qt = ph ? (31 - blockIdx.x) : blockIdx.x;
    int q0 = qt * 64;
    const unsigned short* qp = qb + (size_t)(q0 + wave * 16 + l15) * DHD + quad * 8;
    bf16x8 qf0 = *(const bf16x8*)qp;
    bf16x8 qf1 = *(const bf16x8*)(qp + 32);
    f32x4 oacc[4];
#pragma unroll
    for (int dj = 0; dj < 4; dj++) oacc[dj] = zero4;
    float mrow = -1e30f, lrow = 0.f;

    int nt = qt + 1;
    for (int t = 0; t < nt; t++) {
      int kv0 = t * 64;
      __syncthreads();
      async_copy16(&lK0[tid * 8], kb + (size_t)(kv0 + r4) * DHD + c8);
      async_copy16(&lK1[tid * 8], kb + (size_t)(kv0 + r4) * DHD + 32 + c8);
      async_copy16(&lV0[tid * 8], vb + (size_t)r4 * DS + kv0 + c8);
      async_copy16(&lV1[tid * 8], vb + (size_t)r4 * DS + kv0 + 32 + c8);
      __syncthreads();

      // S^T[kv][q] tiles: a = K rows, b = Q rows
      f32x4 sacc[4];
#pragma unroll
      for (int nj = 0; nj < 4; nj++) {
        sacc[nj] = zero4;
        bf16x8 kf0 = *(const bf16x8*)&lK0[(nj * 16 + l15) * 32 + quad * 8];
        bf16x8 kf1 = *(const bf16x8*)&lK1[(nj * 16 + l15) * 32 + quad * 8];
        sacc[nj] = __builtin_amdgcn_mfma_f32_16x16x32_bf16(kf0, qf0, sacc[nj], 0, 0, 0);
        sacc[nj] = __builtin_amdgcn_mfma_f32_16x16x32_bf16(kf1, qf1, sacc[nj], 0, 0, 0);
      }
      if (t == nt - 1) {   // diagonal tile: mask kv > q (block-uniform branch)
        int ql = wave * 16 + l15;
#pragma unroll
        for (int nj = 0; nj < 4; nj++)
#pragma unroll
          for (int r = 0; r < 4; r++)
            if (nj * 16 + quad * 4 + r > ql) sacc[nj][r] = -1e30f;
      }
      // per-lane scalar online softmax over 16 kv values (col = l15)
      float tm = -1e30f;
#pragma unroll
      for (int nj = 0; nj < 4; nj++)
#pragma unroll
        for (int r = 0; r < 4; r++) tm = fmaxf(tm, sacc[nj][r]);
      tm = fmaxf(tm, __shfl_xor(tm, 16));
      tm = fmaxf(tm, __shfl_xor(tm, 32));
      float mn = fmaxf(mrow, tm);
      float alpha = __builtin_amdgcn_exp2f(mrow - mn);
      mrow = mn;
      float rs = 0.f;
      float p[4][4];
#pragma unroll
      for (int nj = 0; nj < 4; nj++)
#pragma unroll
        for (int r = 0; r < 4; r++) {
          float e = __builtin_amdgcn_exp2f(sacc[nj][r] - mn);
          p[nj][r] = e;
          rs += e;
        }
      rs += __shfl_xor(rs, 16);
      rs += __shfl_xor(rs, 32);
      lrow = lrow * alpha + rs;
      // P[q=l15][kv] -> LDS, 4 x b64 writes (consecutive kv)
#pragma unroll
      for (int nj = 0; nj < 4; nj++) {
        us4 w4;
#pragma unroll
        for (int r = 0; r < 4; r++) w4[r] = f2b(p[nj][r]);
        *(us4*)&lPw[l15 * 72 + nj * 16 + quad * 4] = w4;
      }
      bf16x8 pf0 = *(const bf16x8*)&lPw[l15 * 72 + quad * 8];
      bf16x8 pf1 = *(const bf16x8*)&lPw[l15 * 72 + 32 + quad * 8];
      // O^T += V^T * P^T ; rescale O^T by scalar alpha first
#pragma unroll
      for (int dj = 0; dj < 4; dj++) {
#pragma unroll
        for (int r = 0; r < 4; r++) oacc[dj][r] *= alpha;
        bf16x8 vf0 = *(const bf16x8*)&lV0[(dj * 16 + l15) * 32 + quad * 8];
        bf16x8 vf1 = *(const bf16x8*)&lV1[(dj * 16 + l15) * 32 + quad * 8];
        oacc[dj] = __builtin_amdgcn_mfma_f32_16x16x32_bf16(vf0, pf0, oacc[dj], 0, 0, 0);
        oacc[dj] = __builtin_amdgcn_mfma_f32_16x16x32_bf16(vf1, pf1, oacc[dj], 0, 0, 0);
      }
    }
    // epilogue: O^T[d][q=l15] / lrow -> ctx[b][s][h*64+d], packed b64 stores
    float inv = __builtin_amdgcn_rcpf(lrow);
    size_t orow = ((size_t)b * DS + q0 + wave * 16 + l15) * (DNH * DHD) + (size_t)h * DHD;
#pragma unroll
    for (int dj = 0; dj < 4; dj++) {
      us4 o4;
#pragma unroll
      for (int r = 0; r < 4; r++) o4[r] = f2b(oacc[dj][r] * inv);
      *(us4*)&ctx[orow + dj * 16 + quad * 4] = o4;
    }
  }
}

extern "C" void kernel_launch(void* const* d_in, const int* in_sizes, int n_in,
                              void* d_out, int out_size, void* d_ws, size_t ws_size,
                              hipStream_t stream) {
  (void)in_sizes; (void)n_in; (void)out_size; (void)ws_size;
  const void* hs = d_in[0];
  const int* pos = (const int*)d_in[2];
  const void* wq = d_in[3];
  const void* wk = d_in[4];
  const void* wv = d_in[5];
  const void* wo = d_in[6];

  char* ws = (char*)d_ws;
  size_t off = 0;
  auto take = [&](size_t bytes) -> char* {
    char* p = ws + off;
    off += (bytes + 255) & ~(size_t)255;
    return p;
  };
  int* flags            = (int*)take(256);
  unsigned short* xb    = (unsigned short*)take((size_t)DM * DH * 2);
  unsigned short* wtqkv = (unsigned short*)take((size_t)DNQKV * DH * 2);
  unsigned short* wto   = (unsigned short*)take((size_t)DH * DH * 2);
  unsigned short* c1    = (unsigned short*)take((size_t)DM * DNQKV * 2);
  unsigned short* qws   = (unsigned short*)take((size_t)DB * DNH * DS * DHD * 2);
  unsigned short* kws   = (unsigned short*)take((size_t)DB * DKVH * DS * DHD * 2);
  unsigned short* vtws  = (unsigned short*)take((size_t)DB * DKVH * DS * DHD * 2);
  unsigned short* ctx   = (unsigned short*)take((size_t)DM * DNH * DHD * 2);

  detect_mode<<<1, 64, 0, stream>>>((const unsigned short*)wq, flags);
  convert_x<<<DM * DH / 8 / 256, 256, 0, stream>>>(hs, xb, flags, DM * DH);
  transpose_w<<<dim3(64, 64), 256, 0, stream>>>(wq, wtqkv, flags, 2048, 2048);
  transpose_w<<<dim3(16, 64), 256, 0, stream>>>(wk, wtqkv + (size_t)2048 * 2048, flags, 2048, 512);
  transpose_w<<<dim3(16, 64), 256, 0, stream>>>(wv, wtqkv + (size_t)2560 * 2048, flags, 2048, 512);
  transpose_w<<<dim3(64, 64), 256, 0, stream>>>(wo, wto, flags, 2048, 2048);

  gemm_bt<<<dim3(DNQKV / 128, DM / 128), 256, 0, stream>>>(
      xb, wtqkv, c1, (float*)nullptr, flags + 1, DM, DNQKV, DH);

  rope_qk<<<DM * 40 * 32 / 256, 256, 0, stream>>>(c1, pos, qws, kws);
  transpose_v<<<dim3(DS / 64, DB * DKVH), 256, 0, stream>>>(c1, vtws);

  flash_attn<<<dim3(16, DB * DNH), 256, 0, stream>>>(qws, kws, vtws, ctx);

  gemm_bt<<<dim3(DH / 128, DM / 128), 256, 0, stream>>>(
      ctx, wto, (unsigned short*)d_out, (float*)d_out, flags, DM, DH, DH);
}

// Round 3
// 372.464 us; speedup vs baseline: 1.8134x; 1.0034x over previous
//
#include <hip/hip_runtime.h>
#include <hip/hip_bf16.h>

// ---- problem constants ----
#define DB   2
#define DS   2048
#define DH   2048
#define DNH  32
#define DKVH 8
#define DHD  64
#define DM   4096    // B*S
#define DNQKV 3072   // NH*HD + 2*KVH*HD

typedef __attribute__((ext_vector_type(8))) short bf16x8;
typedef __attribute__((ext_vector_type(4))) float f32x4;
typedef __attribute__((ext_vector_type(8))) unsigned short us8;
typedef __attribute__((ext_vector_type(4))) unsigned short us4;

__device__ __forceinline__ float b2f(unsigned short u) {
  unsigned int x = ((unsigned int)u) << 16;
  return __builtin_bit_cast(float, x);
}
__device__ __forceinline__ unsigned short f2b(float f) {
  unsigned int u = __builtin_bit_cast(unsigned int, f);
  return (unsigned short)((u + 0x8000u) >> 16);
}
__device__ __forceinline__ void async_copy16(void* lds, const void* g) {
  __builtin_amdgcn_global_load_lds((const __attribute__((address_space(1))) void*)g,
                                   (__attribute__((address_space(3))) void*)lds,
                                   16, 0, 0);
}

// ---- dtype detector ----
__global__ void detect_mode(const unsigned short* __restrict__ w, int* __restrict__ flags) {
  int t = threadIdx.x;
  int trips = 0;
  for (int i = 0; i < 4; i++) {
    unsigned short u = w[t * 4 + i];
    int e = (u >> 7) & 0xFF;
    if (e >= 161 || (e <= 93 && e != 0)) trips++;
  }
  for (int off = 32; off > 0; off >>= 1) trips += __shfl_down(trips, off);
  if (t == 0) flags[0] = (trips >= 8) ? 1 : 0;  // 1 = fp32 I/O, 0 = bf16
}

// ---- X -> bf16 ----
__global__ __launch_bounds__(256) void convert_x(const void* __restrict__ xin,
                                                 unsigned short* __restrict__ xb,
                                                 const int* __restrict__ flags, int n) {
  int mode = flags[0];
  int i = (blockIdx.x * 256 + threadIdx.x) * 8;
  if (i >= n) return;
  if (mode) {
    const float* f = (const float*)xin;
    us8 o;
#pragma unroll
    for (int j = 0; j < 8; j++) o[j] = f2b(f[i + j]);
    *(us8*)&xb[i] = o;
  } else {
    *(us8*)&xb[i] = *(const us8*)((const unsigned short*)xin + i);
  }
}

// ---- W [R][C] -> bf16 W^T [C][R] ----
__global__ __launch_bounds__(256) void transpose_w(const void* __restrict__ win,
                                                   unsigned short* __restrict__ out,
                                                   const int* __restrict__ flags,
                                                   int R, int C) {
  __shared__ float tile[32][33];
  int mode = flags[0];
  int c0 = blockIdx.x * 32, r0 = blockIdx.y * 32;
  int tx = threadIdx.x & 31, ty = threadIdx.x >> 5;
  if (mode) {
    const float* f = (const float*)win;
    for (int i = ty; i < 32; i += 8) tile[i][tx] = f[(size_t)(r0 + i) * C + c0 + tx];
  } else {
    const unsigned short* bsrc = (const unsigned short*)win;
    for (int i = ty; i < 32; i += 8) tile[i][tx] = b2f(bsrc[(size_t)(r0 + i) * C + c0 + tx]);
  }
  __syncthreads();
  for (int i = ty; i < 32; i += 8) out[(size_t)(c0 + i) * R + r0 + tx] = f2b(tile[tx][i]);
}

#define QSC 0.18033688011112042f   // (1/8) * log2(e)

// ---- fused QKV GEMM + RoPE + head-major scatter ----
// C[4096,3072] = X * Wqkv^T; epilogue applies RoPE to Q/K and scatters
// q -> qws[b][h][s][d] (pre-scaled by QSC), k -> kws[b][kh][s][d], v -> vws[b][vh][s][d].
__global__ __launch_bounds__(256)
void gemm_qkv(const unsigned short* __restrict__ A, const unsigned short* __restrict__ Bt,
              const int* __restrict__ pos_ids,
              unsigned short* __restrict__ qws, unsigned short* __restrict__ kws,
              unsigned short* __restrict__ vws) {
  __shared__ __align__(16) unsigned short lA[128 * 32];
  __shared__ __align__(16) unsigned short lB[128 * 32];
  int tid = threadIdx.x, lane = tid & 63, wave = tid >> 6;
  int wm = wave >> 1, wn = wave & 1;
  int quad = lane >> 4, l15 = lane & 15;
  // XCD swizzle: bid%8 -> contiguous tile band per XCD (L2 A-locality)
  int bid = blockIdx.y * 24 + blockIdx.x;
  int tile = (bid & 7) * 96 + (bid >> 3);
  int bxt = tile % 24, byt = tile / 24;
  size_t tm0 = (size_t)byt * 128, tn0 = (size_t)bxt * 128;

  f32x4 zero4 = {0.f, 0.f, 0.f, 0.f};
  f32x4 acc[4][4];
#pragma unroll
  for (int mi = 0; mi < 4; mi++)
#pragma unroll
    for (int ni = 0; ni < 4; ni++) acc[mi][ni] = zero4;

  for (int kt = 0; kt < 64; kt++) {
    __syncthreads();
#pragma unroll
    for (int i = 0; i < 2; i++) {
      int c = tid + 256 * i;
      int r = c >> 2, cb = (c & 3) * 8;
      async_copy16(&lA[c * 8], A + (tm0 + r) * DH + kt * 32 + cb);
      async_copy16(&lB[c * 8], Bt + (tn0 + r) * DH + kt * 32 + cb);
    }
    __syncthreads();
    bf16x8 af[4], bfr[4];
#pragma unroll
    for (int mi = 0; mi < 4; mi++)
      af[mi] = *(const bf16x8*)&lA[(wm * 64 + mi * 16 + l15) * 32 + quad * 8];
#pragma unroll
    for (int ni = 0; ni < 4; ni++)
      bfr[ni] = *(const bf16x8*)&lB[(wn * 64 + ni * 16 + l15) * 32 + quad * 8];
#pragma unroll
    for (int mi = 0; mi < 4; mi++)
#pragma unroll
      for (int ni = 0; ni < 4; ni++)
        acc[mi][ni] = __builtin_amdgcn_mfma_f32_16x16x32_bf16(af[mi], bfr[ni], acc[mi][ni], 0, 0, 0);
  }

  int hs = bxt * 2 + wn;  // head slot 0..47 (wave-uniform)
  if (hs < 40) {
    // RoPE region: Q (hs<32) or K
    float sc = (hs < 32) ? QSC : 1.0f;
    unsigned short* dst0 = (hs < 32) ? qws : kws;
    int hh = (hs < 32) ? hs : (hs - 32);
    // invf(d) = 10000^(-d/32); invf(16+l15) = 0.01*invf(l15) exactly
    float invf0 = __expf(-(float)l15 * (9.210340371976184f / 32.0f));
    float invf1 = invf0 * 0.01f;
#pragma unroll
    for (int mi = 0; mi < 4; mi++)
#pragma unroll
      for (int r = 0; r < 4; r++) {
        size_t gr = tm0 + wm * 64 + mi * 16 + quad * 4 + r;
        int b = (int)(gr >> 11), s = (int)(gr & 2047);
        float t = (float)pos_ids[gr];
        unsigned short* row = dst0 + ((size_t)(b * ((hs < 32) ? DNH : DKVH) + hh) * DS + s) * DHD;
#pragma unroll
        for (int ni = 0; ni < 2; ni++) {
          float x1 = acc[mi][ni][r], x2 = acc[mi][ni + 2][r];
          float ang = t * (ni ? invf1 : invf0);
          float sn, cs;
          __sincosf(ang, &sn, &cs);
          int d = ni * 16 + l15;
          row[d]      = f2b((x1 * cs - x2 * sn) * sc);
          row[d + 32] = f2b((x2 * cs + x1 * sn) * sc);
        }
      }
  } else {
    int vh = hs - 40;
#pragma unroll
    for (int mi = 0; mi < 4; mi++)
#pragma unroll
      for (int r = 0; r < 4; r++) {
        size_t gr = tm0 + wm * 64 + mi * 16 + quad * 4 + r;
        int b = (int)(gr >> 11), s = (int)(gr & 2047);
        unsigned short* row = vws + ((size_t)(b * DKVH + vh) * DS + s) * DHD;
#pragma unroll
        for (int ni = 0; ni < 4; ni++) row[ni * 16 + l15] = f2b(acc[mi][ni][r]);
      }
  }
}

// ---- out GEMM: d_out[M,N] = ctx * Wo^T, fp32 or bf16 out ----
__global__ __launch_bounds__(256)
void gemm_out(const unsigned short* __restrict__ A, const unsigned short* __restrict__ Bt,
              unsigned short* __restrict__ Cb, float* __restrict__ Cf,
              const int* __restrict__ outmode) {
  __shared__ __align__(16) unsigned short lA[128 * 32];
  __shared__ __align__(16) unsigned short lB[128 * 32];
  int tid = threadIdx.x, lane = tid & 63, wave = tid >> 6;
  int wm = wave >> 1, wn = wave & 1;
  int quad = lane >> 4, l15 = lane & 15;
  int bid = blockIdx.y * 16 + blockIdx.x;
  int tile = (bid & 7) * 64 + (bid >> 3);
  int bxt = tile & 15, byt = tile >> 4;
  size_t tm0 = (size_t)byt * 128, tn0 = (size_t)bxt * 128;

  f32x4 zero4 = {0.f, 0.f, 0.f, 0.f};
  f32x4 acc[4][4];
#pragma unroll
  for (int mi = 0; mi < 4; mi++)
#pragma unroll
    for (int ni = 0; ni < 4; ni++) acc[mi][ni] = zero4;

  for (int kt = 0; kt < 64; kt++) {
    __syncthreads();
#pragma unroll
    for (int i = 0; i < 2; i++) {
      int c = tid + 256 * i;
      int r = c >> 2, cb = (c & 3) * 8;
      async_copy16(&lA[c * 8], A + (tm0 + r) * DH + kt * 32 + cb);
      async_copy16(&lB[c * 8], Bt + (tn0 + r) * DH + kt * 32 + cb);
    }
    __syncthreads();
    bf16x8 af[4], bfr[4];
#pragma unroll
    for (int mi = 0; mi < 4; mi++)
      af[mi] = *(const bf16x8*)&lA[(wm * 64 + mi * 16 + l15) * 32 + quad * 8];
#pragma unroll
    for (int ni = 0; ni < 4; ni++)
      bfr[ni] = *(const bf16x8*)&lB[(wn * 64 + ni * 16 + l15) * 32 + quad * 8];
#pragma unroll
    for (int mi = 0; mi < 4; mi++)
#pragma unroll
      for (int ni = 0; ni < 4; ni++)
        acc[mi][ni] = __builtin_amdgcn_mfma_f32_16x16x32_bf16(af[mi], bfr[ni], acc[mi][ni], 0, 0, 0);
  }
  int mode = *outmode;
#pragma unroll
  for (int mi = 0; mi < 4; mi++)
#pragma unroll
    for (int ni = 0; ni < 4; ni++)
#pragma unroll
      for (int r = 0; r < 4; r++) {
        size_t gr = tm0 + wm * 64 + mi * 16 + quad * 4 + r;
        size_t gc = tn0 + wn * 64 + ni * 16 + l15;
        float v = acc[mi][ni][r];
        if (mode) Cf[gr * DH + gc] = v;
        else      Cb[gr * DH + gc] = f2b(v);
      }
}

// ---- V [b][kvh][s][d] -> V^T [b][kvh][d][s] ----
__global__ __launch_bounds__(256) void transpose_v(const unsigned short* __restrict__ vws,
                                                   unsigned short* __restrict__ vt) {
  __shared__ unsigned short tile[64 * 72];
  int s0 = blockIdx.x * 64;
  int bk = blockIdx.y;               // b*8+kvh
  const unsigned short* src = vws + ((size_t)bk * DS + s0) * DHD;
#pragma unroll
  for (int i = 0; i < 2; i++) {
    int c = threadIdx.x + 256 * i;
    int s = c >> 3, d0 = (c & 7) * 8;
    *(us8*)&tile[s * 72 + d0] = *(const us8*)(src + (size_t)s * DHD + d0);
  }
  __syncthreads();
  unsigned short* dst = vt + (size_t)bk * DHD * DS + s0;
#pragma unroll
  for (int i = 0; i < 2; i++) {
    int c = threadIdx.x + 256 * i;
    int d = c >> 3, sc = (c & 7) * 8;
    us8 o;
#pragma unroll
    for (int j = 0; j < 8; j++) o[j] = tile[(sc + j) * 72 + d];
    *(us8*)&dst[(size_t)d * DS + sc] = o;
  }
}

// ---- causal GQA flash attention (S^T form, paired q-tiles) ----
__global__ __launch_bounds__(256, 4)
void flash_attn(const unsigned short* __restrict__ q, const unsigned short* __restrict__ k,
                const unsigned short* __restrict__ vt, unsigned short* __restrict__ ctx) {
  __shared__ __align__(16) unsigned short lK0[64 * 32];
  __shared__ __align__(16) unsigned short lK1[64 * 32];
  __shared__ __align__(16) unsigned short lV0[64 * 32];
  __shared__ __align__(16) unsigned short lV1[64 * 32];
  __shared__ __align__(16) unsigned short lP[4 * 16 * 72];
  int tid = threadIdx.x, lane = tid & 63, wave = tid >> 6;
  int quad = lane >> 4, l15 = lane & 15;
  int bh = blockIdx.y, b = bh >> 5, h = bh & 31, kvh = h >> 2;
  const unsigned short* qb = q + (size_t)(b * DNH + h) * DS * DHD;
  const unsigned short* kb = k + (size_t)(b * DKVH + kvh) * DS * DHD;
  const unsigned short* vb = vt + (size_t)(b * DKVH + kvh) * DHD * DS;
  unsigned short* lPw = lP + wave * 16 * 72;
  int r4 = tid >> 2, c8 = (tid & 3) * 8;

  f32x4 zero4 = {0.f, 0.f, 0.f, 0.f};
  for (int ph = 0; ph < 2; ph++) {
    int qt = ph ? (31 - blockIdx.x) : blockIdx.x;
    int q0 = qt * 64;
    const unsigned short* qp = qb + (size_t)(q0 + wave * 16 + l15) * DHD + quad * 8;
    bf16x8 qf0 = *(const bf16x8*)qp;
    bf16x8 qf1 = *(const bf16x8*)(qp + 32);
    f32x4 oacc[4];
#pragma unroll
    for (int dj = 0; dj < 4; dj++) oacc[dj] = zero4;
    float mrow = -1e30f, lrow = 0.f;

    int nt = qt + 1;
    for (int t = 0; t < nt; t++) {
      int kv0 = t * 64;
      __syncthreads();
      async_copy16(&lK0[tid * 8], kb + (size_t)(kv0 + r4) * DHD + c8);
      async_copy16(&lK1[tid * 8], kb + (size_t)(kv0 + r4) * DHD + 32 + c8);
      async_copy16(&lV0[tid * 8], vb + (size_t)r4 * DS + kv0 + c8);
      async_copy16(&lV1[tid * 8], vb + (size_t)r4 * DS + kv0 + 32 + c8);
      __syncthreads();

      f32x4 sacc[4];
#pragma unroll
      for (int nj = 0; nj < 4; nj++) {
        sacc[nj] = zero4;
        bf16x8 kf0 = *(const bf16x8*)&lK0[(nj * 16 + l15) * 32 + quad * 8];
        bf16x8 kf1 = *(const bf16x8*)&lK1[(nj * 16 + l15) * 32 + quad * 8];
        sacc[nj] = __builtin_amdgcn_mfma_f32_16x16x32_bf16(kf0, qf0, sacc[nj], 0, 0, 0);
        sacc[nj] = __builtin_amdgcn_mfma_f32_16x16x32_bf16(kf1, qf1, sacc[nj], 0, 0, 0);
      }
      if (t == nt - 1) {
        int ql = wave * 16 + l15;
#pragma unroll
        for (int nj = 0; nj < 4; nj++)
#pragma unroll
          for (int r = 0; r < 4; r++)
            if (nj * 16 + quad * 4 + r > ql) sacc[nj][r] = -1e30f;
      }
      float tm = -1e30f;
#pragma unroll
      for (int nj = 0; nj < 4; nj++)
#pragma unroll
        for (int r = 0; r < 4; r++) tm = fmaxf(tm, sacc[nj][r]);
      tm = fmaxf(tm, __shfl_xor(tm, 16));
      tm = fmaxf(tm, __shfl_xor(tm, 32));
      float mn = fmaxf(mrow, tm);
      float alpha = __builtin_amdgcn_exp2f(mrow - mn);
      mrow = mn;
      float rs = 0.f;
      float p[4][4];
#pragma unroll
      for (int nj = 0; nj < 4; nj++)
#pragma unroll
        for (int r = 0; r < 4; r++) {
          float e = __builtin_amdgcn_exp2f(sacc[nj][r] - mn);
          p[nj][r] = e;
          rs += e;
        }
      rs += __shfl_xor(rs, 16);
      rs += __shfl_xor(rs, 32);
      lrow = lrow * alpha + rs;
#pragma unroll
      for (int nj = 0; nj < 4; nj++) {
        us4 w4;
#pragma unroll
        for (int r = 0; r < 4; r++) w4[r] = f2b(p[nj][r]);
        *(us4*)&lPw[l15 * 72 + nj * 16 + quad * 4] = w4;
      }
      bf16x8 pf0 = *(const bf16x8*)&lPw[l15 * 72 + quad * 8];
      bf16x8 pf1 = *(const bf16x8*)&lPw[l15 * 72 + 32 + quad * 8];
#pragma unroll
      for (int dj = 0; dj < 4; dj++) {
#pragma unroll
        for (int r = 0; r < 4; r++) oacc[dj][r] *= alpha;
        bf16x8 vf0 = *(const bf16x8*)&lV0[(dj * 16 + l15) * 32 + quad * 8];
        bf16x8 vf1 = *(const bf16x8*)&lV1[(dj * 16 + l15) * 32 + quad * 8];
        oacc[dj] = __builtin_amdgcn_mfma_f32_16x16x32_bf16(vf0, pf0, oacc[dj], 0, 0, 0);
        oacc[dj] = __builtin_amdgcn_mfma_f32_16x16x32_bf16(vf1, pf1, oacc[dj], 0, 0, 0);
      }
    }
    float inv = __builtin_amdgcn_rcpf(lrow);
    size_t orow = ((size_t)b * DS + q0 + wave * 16 + l15) * (DNH * DHD) + (size_t)h * DHD;
#pragma unroll
    for (int dj = 0; dj < 4; dj++) {
      us4 o4;
#pragma unroll
      for (int r = 0; r < 4; r++) o4[r] = f2b(oacc[dj][r] * inv);
      *(us4*)&ctx[orow + dj * 16 + quad * 4] = o4;
    }
  }
}

extern "C" void kernel_launch(void* const* d_in, const int* in_sizes, int n_in,
                              void* d_out, int out_size, void* d_ws, size_t ws_size,
                              hipStream_t stream) {
  (void)in_sizes; (void)n_in; (void)out_size; (void)ws_size;
  const void* hs = d_in[0];
  const int* pos = (const int*)d_in[2];
  const void* wq = d_in[3];
  const void* wk = d_in[4];
  const void* wv = d_in[5];
  const void* wo = d_in[6];

  char* ws = (char*)d_ws;
  size_t off = 0;
  auto take = [&](size_t bytes) -> char* {
    char* p = ws + off;
    off += (bytes + 255) & ~(size_t)255;
    return p;
  };
  int* flags            = (int*)take(256);
  unsigned short* xb    = (unsigned short*)take((size_t)DM * DH * 2);
  unsigned short* wtqkv = (unsigned short*)take((size_t)DNQKV * DH * 2);
  unsigned short* wto   = (unsigned short*)take((size_t)DH * DH * 2);
  unsigned short* qws   = (unsigned short*)take((size_t)DB * DNH * DS * DHD * 2);
  unsigned short* kws   = (unsigned short*)take((size_t)DB * DKVH * DS * DHD * 2);
  unsigned short* vws   = (unsigned short*)take((size_t)DB * DKVH * DS * DHD * 2);
  unsigned short* vtws  = (unsigned short*)take((size_t)DB * DKVH * DS * DHD * 2);
  unsigned short* ctx   = (unsigned short*)take((size_t)DM * DNH * DHD * 2);

  detect_mode<<<1, 64, 0, stream>>>((const unsigned short*)wq, flags);
  convert_x<<<DM * DH / 8 / 256, 256, 0, stream>>>(hs, xb, flags, DM * DH);
  transpose_w<<<dim3(64, 64), 256, 0, stream>>>(wq, wtqkv, flags, 2048, 2048);
  transpose_w<<<dim3(16, 64), 256, 0, stream>>>(wk, wtqkv + (size_t)2048 * 2048, flags, 2048, 512);
  transpose_w<<<dim3(16, 64), 256, 0, stream>>>(wv, wtqkv + (size_t)2560 * 2048, flags, 2048, 512);
  transpose_w<<<dim3(64, 64), 256, 0, stream>>>(wo, wto, flags, 2048, 2048);

  gemm_qkv<<<dim3(24, 32), 256, 0, stream>>>(xb, wtqkv, pos, qws, kws, vws);

  transpose_v<<<dim3(DS / 64, DB * DKVH), 256, 0, stream>>>(vws, vtws);

  flash_attn<<<dim3(16, DB * DNH), 256, 0, stream>>>(qws, kws, vtws, ctx);

  gemm_out<<<dim3(16, 32), 256, 0, stream>>>(ctx, wto, (unsigned short*)d_out, (float*)d_out, flags);
}

// Round 4
// 371.321 us; speedup vs baseline: 1.8190x; 1.0031x over previous
//
#include <hip/hip_runtime.h>
#include <hip/hip_bf16.h>

// ---- problem constants ----
#define DB   2
#define DS   2048
#define DH   2048
#define DNH  32
#define DKVH 8
#define DHD  64
#define DM   4096    // B*S
#define DNQKV 3072   // NH*HD + 2*KVH*HD

typedef __attribute__((ext_vector_type(8))) short bf16x8;
typedef __attribute__((ext_vector_type(4))) float f32x4;
typedef __attribute__((ext_vector_type(8))) unsigned short us8;
typedef __attribute__((ext_vector_type(4))) unsigned short us4;

__device__ __forceinline__ float b2f(unsigned short u) {
  unsigned int x = ((unsigned int)u) << 16;
  return __builtin_bit_cast(float, x);
}
__device__ __forceinline__ unsigned short f2b(float f) {
  unsigned int u = __builtin_bit_cast(unsigned int, f);
  return (unsigned short)((u + 0x8000u) >> 16);
}
__device__ __forceinline__ void async_copy16(void* lds, const void* g) {
  __builtin_amdgcn_global_load_lds((const __attribute__((address_space(1))) void*)g,
                                   (__attribute__((address_space(3))) void*)lds,
                                   16, 0, 0);
}

// ---- dtype detector ----
__global__ void detect_mode(const unsigned short* __restrict__ w, int* __restrict__ flags) {
  int t = threadIdx.x;
  int trips = 0;
  for (int i = 0; i < 4; i++) {
    unsigned short u = w[t * 4 + i];
    int e = (u >> 7) & 0xFF;
    if (e >= 161 || (e <= 93 && e != 0)) trips++;
  }
  for (int off = 32; off > 0; off >>= 1) trips += __shfl_down(trips, off);
  if (t == 0) flags[0] = (trips >= 8) ? 1 : 0;  // 1 = fp32 I/O, 0 = bf16
}

// ---- X -> bf16 ----
__global__ __launch_bounds__(256) void convert_x(const void* __restrict__ xin,
                                                 unsigned short* __restrict__ xb,
                                                 const int* __restrict__ flags, int n) {
  int mode = flags[0];
  int i = (blockIdx.x * 256 + threadIdx.x) * 8;
  if (i >= n) return;
  if (mode) {
    const float* f = (const float*)xin;
    us8 o;
#pragma unroll
    for (int j = 0; j < 8; j++) o[j] = f2b(f[i + j]);
    *(us8*)&xb[i] = o;
  } else {
    *(us8*)&xb[i] = *(const us8*)((const unsigned short*)xin + i);
  }
}

// ---- W [R][C] -> bf16 W^T [C][R] ----
__global__ __launch_bounds__(256) void transpose_w(const void* __restrict__ win,
                                                   unsigned short* __restrict__ out,
                                                   const int* __restrict__ flags,
                                                   int R, int C) {
  __shared__ float tile[32][33];
  int mode = flags[0];
  int c0 = blockIdx.x * 32, r0 = blockIdx.y * 32;
  int tx = threadIdx.x & 31, ty = threadIdx.x >> 5;
  if (mode) {
    const float* f = (const float*)win;
    for (int i = ty; i < 32; i += 8) tile[i][tx] = f[(size_t)(r0 + i) * C + c0 + tx];
  } else {
    const unsigned short* bsrc = (const unsigned short*)win;
    for (int i = ty; i < 32; i += 8) tile[i][tx] = b2f(bsrc[(size_t)(r0 + i) * C + c0 + tx]);
  }
  __syncthreads();
  for (int i = ty; i < 32; i += 8) out[(size_t)(c0 + i) * R + r0 + tx] = f2b(tile[tx][i]);
}

#define QSC 0.18033688011112042f   // (1/8) * log2(e)

// ---- fused QKV GEMM + RoPE + head-major scatter (BK=64, natural tile order) ----
__global__ __launch_bounds__(256)
void gemm_qkv(const unsigned short* __restrict__ A, const unsigned short* __restrict__ Bt,
              const int* __restrict__ pos_ids,
              unsigned short* __restrict__ qws, unsigned short* __restrict__ kws,
              unsigned short* __restrict__ vws) {
  __shared__ __align__(16) unsigned short lA[128 * 64];
  __shared__ __align__(16) unsigned short lB[128 * 64];
  int tid = threadIdx.x, lane = tid & 63, wave = tid >> 6;
  int wm = wave >> 1, wn = wave & 1;
  int quad = lane >> 4, l15 = lane & 15;
  size_t tm0 = (size_t)blockIdx.y * 128, tn0 = (size_t)blockIdx.x * 128;

  f32x4 zero4 = {0.f, 0.f, 0.f, 0.f};
  f32x4 acc[4][4];
#pragma unroll
  for (int mi = 0; mi < 4; mi++)
#pragma unroll
    for (int ni = 0; ni < 4; ni++) acc[mi][ni] = zero4;

  for (int kt = 0; kt < 32; kt++) {
    __syncthreads();
#pragma unroll
    for (int i = 0; i < 4; i++) {
      int c = tid + 256 * i;
      int r = c >> 3, cb = (c & 7) * 8;
      async_copy16(&lA[c * 8], A + (tm0 + r) * DH + kt * 64 + cb);
      async_copy16(&lB[c * 8], Bt + (tn0 + r) * DH + kt * 64 + cb);
    }
    __syncthreads();
#pragma unroll
    for (int ks = 0; ks < 2; ks++) {
      bf16x8 af[4], bfr[4];
#pragma unroll
      for (int mi = 0; mi < 4; mi++)
        af[mi] = *(const bf16x8*)&lA[(wm * 64 + mi * 16 + l15) * 64 + ks * 32 + quad * 8];
#pragma unroll
      for (int ni = 0; ni < 4; ni++)
        bfr[ni] = *(const bf16x8*)&lB[(wn * 64 + ni * 16 + l15) * 64 + ks * 32 + quad * 8];
#pragma unroll
      for (int mi = 0; mi < 4; mi++)
#pragma unroll
        for (int ni = 0; ni < 4; ni++)
          acc[mi][ni] = __builtin_amdgcn_mfma_f32_16x16x32_bf16(af[mi], bfr[ni], acc[mi][ni], 0, 0, 0);
    }
  }

  int hs = (int)(tn0 >> 6) + wn;  // head slot 0..47 (wave-uniform)
  if (hs < 40) {
    float sc = (hs < 32) ? QSC : 1.0f;
    unsigned short* dst0 = (hs < 32) ? qws : kws;
    int hh = (hs < 32) ? hs : (hs - 32);
    float invf0 = __expf(-(float)l15 * (9.210340371976184f / 32.0f));
    float invf1 = invf0 * 0.01f;
#pragma unroll
    for (int mi = 0; mi < 4; mi++)
#pragma unroll
      for (int r = 0; r < 4; r++) {
        size_t gr = tm0 + wm * 64 + mi * 16 + quad * 4 + r;
        int b = (int)(gr >> 11), s = (int)(gr & 2047);
        float t = (float)pos_ids[gr];
        unsigned short* row = dst0 + ((size_t)(b * ((hs < 32) ? DNH : DKVH) + hh) * DS + s) * DHD;
#pragma unroll
        for (int ni = 0; ni < 2; ni++) {
          float x1 = acc[mi][ni][r], x2 = acc[mi][ni + 2][r];
          float ang = t * (ni ? invf1 : invf0);
          float sn, cs;
          __sincosf(ang, &sn, &cs);
          int d = ni * 16 + l15;
          row[d]      = f2b((x1 * cs - x2 * sn) * sc);
          row[d + 32] = f2b((x2 * cs + x1 * sn) * sc);
        }
      }
  } else {
    int vh = hs - 40;
#pragma unroll
    for (int mi = 0; mi < 4; mi++)
#pragma unroll
      for (int r = 0; r < 4; r++) {
        size_t gr = tm0 + wm * 64 + mi * 16 + quad * 4 + r;
        int b = (int)(gr >> 11), s = (int)(gr & 2047);
        unsigned short* row = vws + ((size_t)(b * DKVH + vh) * DS + s) * DHD;
#pragma unroll
        for (int ni = 0; ni < 4; ni++) row[ni * 16 + l15] = f2b(acc[mi][ni][r]);
      }
  }
}

// ---- out GEMM: d_out[M,N] = ctx * Wo^T (BK=64, natural tile order) ----
__global__ __launch_bounds__(256)
void gemm_out(const unsigned short* __restrict__ A, const unsigned short* __restrict__ Bt,
              unsigned short* __restrict__ Cb, float* __restrict__ Cf,
              const int* __restrict__ outmode) {
  __shared__ __align__(16) unsigned short lA[128 * 64];
  __shared__ __align__(16) unsigned short lB[128 * 64];
  int tid = threadIdx.x, lane = tid & 63, wave = tid >> 6;
  int wm = wave >> 1, wn = wave & 1;
  int quad = lane >> 4, l15 = lane & 15;
  size_t tm0 = (size_t)blockIdx.y * 128, tn0 = (size_t)blockIdx.x * 128;

  f32x4 zero4 = {0.f, 0.f, 0.f, 0.f};
  f32x4 acc[4][4];
#pragma unroll
  for (int mi = 0; mi < 4; mi++)
#pragma unroll
    for (int ni = 0; ni < 4; ni++) acc[mi][ni] = zero4;

  for (int kt = 0; kt < 32; kt++) {
    __syncthreads();
#pragma unroll
    for (int i = 0; i < 4; i++) {
      int c = tid + 256 * i;
      int r = c >> 3, cb = (c & 7) * 8;
      async_copy16(&lA[c * 8], A + (tm0 + r) * DH + kt * 64 + cb);
      async_copy16(&lB[c * 8], Bt + (tn0 + r) * DH + kt * 64 + cb);
    }
    __syncthreads();
#pragma unroll
    for (int ks = 0; ks < 2; ks++) {
      bf16x8 af[4], bfr[4];
#pragma unroll
      for (int mi = 0; mi < 4; mi++)
        af[mi] = *(const bf16x8*)&lA[(wm * 64 + mi * 16 + l15) * 64 + ks * 32 + quad * 8];
#pragma unroll
      for (int ni = 0; ni < 4; ni++)
        bfr[ni] = *(const bf16x8*)&lB[(wn * 64 + ni * 16 + l15) * 64 + ks * 32 + quad * 8];
#pragma unroll
      for (int mi = 0; mi < 4; mi++)
#pragma unroll
        for (int ni = 0; ni < 4; ni++)
          acc[mi][ni] = __builtin_amdgcn_mfma_f32_16x16x32_bf16(af[mi], bfr[ni], acc[mi][ni], 0, 0, 0);
    }
  }
  int mode = *outmode;
#pragma unroll
  for (int mi = 0; mi < 4; mi++)
#pragma unroll
    for (int ni = 0; ni < 4; ni++)
#pragma unroll
      for (int r = 0; r < 4; r++) {
        size_t gr = tm0 + wm * 64 + mi * 16 + quad * 4 + r;
        size_t gc = tn0 + wn * 64 + ni * 16 + l15;
        float v = acc[mi][ni][r];
        if (mode) Cf[gr * DH + gc] = v;
        else      Cb[gr * DH + gc] = f2b(v);
      }
}

// ---- V [b][kvh][s][d] -> V^T [b][kvh][d][s] ----
__global__ __launch_bounds__(256) void transpose_v(const unsigned short* __restrict__ vws,
                                                   unsigned short* __restrict__ vt) {
  __shared__ unsigned short tile[64 * 72];
  int s0 = blockIdx.x * 64;
  int bk = blockIdx.y;               // b*8+kvh
  const unsigned short* src = vws + ((size_t)bk * DS + s0) * DHD;
#pragma unroll
  for (int i = 0; i < 2; i++) {
    int c = threadIdx.x + 256 * i;
    int s = c >> 3, d0 = (c & 7) * 8;
    *(us8*)&tile[s * 72 + d0] = *(const us8*)(src + (size_t)s * DHD + d0);
  }
  __syncthreads();
  unsigned short* dst = vt + (size_t)bk * DHD * DS + s0;
#pragma unroll
  for (int i = 0; i < 2; i++) {
    int c = threadIdx.x + 256 * i;
    int d = c >> 3, sc = (c & 7) * 8;
    us8 o;
#pragma unroll
    for (int j = 0; j < 8; j++) o[j] = tile[(sc + j) * 72 + d];
    *(us8*)&dst[(size_t)d * DS + sc] = o;
  }
}

// ---- causal GQA flash attention (S^T form, paired q-tiles) ----
__global__ __launch_bounds__(256, 4)
void flash_attn(const unsigned short* __restrict__ q, const unsigned short* __restrict__ k,
                const unsigned short* __restrict__ vt, unsigned short* __restrict__ ctx) {
  __shared__ __align__(16) unsigned short lK0[64 * 32];
  __shared__ __align__(16) unsigned short lK1[64 * 32];
  __shared__ __align__(16) unsigned short lV0[64 * 32];
  __shared__ __align__(16) unsigned short lV1[64 * 32];
  __shared__ __align__(16) unsigned short lP[4 * 16 * 72];
  int tid = threadIdx.x, lane = tid & 63, wave = tid >> 6;
  int quad = lane >> 4, l15 = lane & 15;
  int bh = blockIdx.y, b = bh >> 5, h = bh & 31, kvh = h >> 2;
  const unsigned short* qb = q + (size_t)(b * DNH + h) * DS * DHD;
  const unsigned short* kb = k + (size_t)(b * DKVH + kvh) * DS * DHD;
  const unsigned short* vb = vt + (size_t)(b * DKVH + kvh) * DHD * DS;
  unsigned short* lPw = lP + wave * 16 * 72;
  int r4 = tid >> 2, c8 = (tid & 3) * 8;

  f32x4 zero4 = {0.f, 0.f, 0.f, 0.f};
  for (int ph = 0; ph < 2; ph++) {
    int qt = ph ? (31 - blockIdx.x) : blockIdx.x;
    int q0 = qt * 64;
    const unsigned short* qp = qb + (size_t)(q0 + wave * 16 + l15) * DHD + quad * 8;
    bf16x8 qf0 = *(const bf16x8*)qp;
    bf16x8 qf1 = *(const bf16x8*)(qp + 32);
    f32x4 oacc[4];
#pragma unroll
    for (int dj = 0; dj < 4; dj++) oacc[dj] = zero4;
    float mrow = -1e30f, lrow = 0.f;

    int nt = qt + 1;
    for (int t = 0; t < nt; t++) {
      int kv0 = t * 64;
      __syncthreads();
      async_copy16(&lK0[tid * 8], kb + (size_t)(kv0 + r4) * DHD + c8);
      async_copy16(&lK1[tid * 8], kb + (size_t)(kv0 + r4) * DHD + 32 + c8);
      async_copy16(&lV0[tid * 8], vb + (size_t)r4 * DS + kv0 + c8);
      async_copy16(&lV1[tid * 8], vb + (size_t)r4 * DS + kv0 + 32 + c8);
      __syncthreads();

      f32x4 sacc[4];
#pragma unroll
      for (int nj = 0; nj < 4; nj++) {
        sacc[nj] = zero4;
        bf16x8 kf0 = *(const bf16x8*)&lK0[(nj * 16 + l15) * 32 + quad * 8];
        bf16x8 kf1 = *(const bf16x8*)&lK1[(nj * 16 + l15) * 32 + quad * 8];
        sacc[nj] = __builtin_amdgcn_mfma_f32_16x16x32_bf16(kf0, qf0, sacc[nj], 0, 0, 0);
        sacc[nj] = __builtin_amdgcn_mfma_f32_16x16x32_bf16(kf1, qf1, sacc[nj], 0, 0, 0);
      }
      if (t == nt - 1) {
        int ql = wave * 16 + l15;
#pragma unroll
        for (int nj = 0; nj < 4; nj++)
#pragma unroll
          for (int r = 0; r < 4; r++)
            if (nj * 16 + quad * 4 + r > ql) sacc[nj][r] = -1e30f;
      }
      float tm = -1e30f;
#pragma unroll
      for (int nj = 0; nj < 4; nj++)
#pragma unroll
        for (int r = 0; r < 4; r++) tm = fmaxf(tm, sacc[nj][r]);
      tm = fmaxf(tm, __shfl_xor(tm, 16));
      tm = fmaxf(tm, __shfl_xor(tm, 32));
      float mn = fmaxf(mrow, tm);
      float alpha = __builtin_amdgcn_exp2f(mrow - mn);
      mrow = mn;
      float rs = 0.f;
      float p[4][4];
#pragma unroll
      for (int nj = 0; nj < 4; nj++)
#pragma unroll
        for (int r = 0; r < 4; r++) {
          float e = __builtin_amdgcn_exp2f(sacc[nj][r] - mn);
          p[nj][r] = e;
          rs += e;
        }
      rs += __shfl_xor(rs, 16);
      rs += __shfl_xor(rs, 32);
      lrow = lrow * alpha + rs;
#pragma unroll
      for (int nj = 0; nj < 4; nj++) {
        us4 w4;
#pragma unroll
        for (int r = 0; r < 4; r++) w4[r] = f2b(p[nj][r]);
        *(us4*)&lPw[l15 * 72 + nj * 16 + quad * 4] = w4;
      }
      bf16x8 pf0 = *(const bf16x8*)&lPw[l15 * 72 + quad * 8];
      bf16x8 pf1 = *(const bf16x8*)&lPw[l15 * 72 + 32 + quad * 8];
#pragma unroll
      for (int dj = 0; dj < 4; dj++) {
#pragma unroll
        for (int r = 0; r < 4; r++) oacc[dj][r] *= alpha;
        bf16x8 vf0 = *(const bf16x8*)&lV0[(dj * 16 + l15) * 32 + quad * 8];
        bf16x8 vf1 = *(const bf16x8*)&lV1[(dj * 16 + l15) * 32 + quad * 8];
        oacc[dj] = __builtin_amdgcn_mfma_f32_16x16x32_bf16(vf0, pf0, oacc[dj], 0, 0, 0);
        oacc[dj] = __builtin_amdgcn_mfma_f32_16x16x32_bf16(vf1, pf1, oacc[dj], 0, 0, 0);
      }
    }
    float inv = __builtin_amdgcn_rcpf(lrow);
    size_t orow = ((size_t)b * DS + q0 + wave * 16 + l15) * (DNH * DHD) + (size_t)h * DHD;
#pragma unroll
    for (int dj = 0; dj < 4; dj++) {
      us4 o4;
#pragma unroll
      for (int r = 0; r < 4; r++) o4[r] = f2b(oacc[dj][r] * inv);
      *(us4*)&ctx[orow + dj * 16 + quad * 4] = o4;
    }
  }
}

extern "C" void kernel_launch(void* const* d_in, const int* in_sizes, int n_in,
                              void* d_out, int out_size, void* d_ws, size_t ws_size,
                              hipStream_t stream) {
  (void)in_sizes; (void)n_in; (void)out_size; (void)ws_size;
  const void* hs = d_in[0];
  const int* pos = (const int*)d_in[2];
  const void* wq = d_in[3];
  const void* wk = d_in[4];
  const void* wv = d_in[5];
  const void* wo = d_in[6];

  char* ws = (char*)d_ws;
  size_t off = 0;
  auto take = [&](size_t bytes) -> char* {
    char* p = ws + off;
    off += (bytes + 255) & ~(size_t)255;
    return p;
  };
  int* flags            = (int*)take(256);
  unsigned short* xb    = (unsigned short*)take((size_t)DM * DH * 2);
  unsigned short* wtqkv = (unsigned short*)take((size_t)DNQKV * DH * 2);
  unsigned short* wto   = (unsigned short*)take((size_t)DH * DH * 2);
  unsigned short* qws   = (unsigned short*)take((size_t)DB * DNH * DS * DHD * 2);
  unsigned short* kws   = (unsigned short*)take((size_t)DB * DKVH * DS * DHD * 2);
  unsigned short* vws   = (unsigned short*)take((size_t)DB * DKVH * DS * DHD * 2);
  unsigned short* vtws  = (unsigned short*)take((size_t)DB * DKVH * DS * DHD * 2);
  unsigned short* ctx   = (unsigned short*)take((size_t)DM * DNH * DHD * 2);

  detect_mode<<<1, 64, 0, stream>>>((const unsigned short*)wq, flags);
  convert_x<<<DM * DH / 8 / 256, 256, 0, stream>>>(hs, xb, flags, DM * DH);
  transpose_w<<<dim3(64, 64), 256, 0, stream>>>(wq, wtqkv, flags, 2048, 2048);
  transpose_w<<<dim3(16, 64), 256, 0, stream>>>(wk, wtqkv + (size_t)2048 * 2048, flags, 2048, 512);
  transpose_w<<<dim3(16, 64), 256, 0, stream>>>(wv, wtqkv + (size_t)2560 * 2048, flags, 2048, 512);
  transpose_w<<<dim3(64, 64), 256, 0, stream>>>(wo, wto, flags, 2048, 2048);

  gemm_qkv<<<dim3(24, 32), 256, 0, stream>>>(xb, wtqkv, pos, qws, kws, vws);

  transpose_v<<<dim3(DS / 64, DB * DKVH), 256, 0, stream>>>(vws, vtws);

  flash_attn<<<dim3(16, DB * DNH), 256, 0, stream>>>(qws, kws, vtws, ctx);

  gemm_out<<<dim3(16, 32), 256, 0, stream>>>(ctx, wto, (unsigned short*)d_out, (float*)d_out, flags);
}

// Round 5
// 356.084 us; speedup vs baseline: 1.8968x; 1.0428x over previous
//
#include <hip/hip_runtime.h>
#include <hip/hip_bf16.h>

// ---- problem constants ----
#define DB   2
#define DS   2048
#define DH   2048
#define DNH  32
#define DKVH 8
#define DHD  64
#define DM   4096    // B*S
#define DNQKV 3072   // NH*HD + 2*KVH*HD

typedef __attribute__((ext_vector_type(8))) short bf16x8;
typedef __attribute__((ext_vector_type(4))) float f32x4;
typedef __attribute__((ext_vector_type(8))) unsigned short us8;
typedef __attribute__((ext_vector_type(4))) unsigned short us4;

__device__ __forceinline__ float b2f(unsigned short u) {
  unsigned int x = ((unsigned int)u) << 16;
  return __builtin_bit_cast(float, x);
}
__device__ __forceinline__ unsigned short f2b(float f) {
  unsigned int u = __builtin_bit_cast(unsigned int, f);
  return (unsigned short)((u + 0x8000u) >> 16);
}
__device__ __forceinline__ void async_copy16(void* lds, const void* g) {
  __builtin_amdgcn_global_load_lds((const __attribute__((address_space(1))) void*)g,
                                   (__attribute__((address_space(3))) void*)lds,
                                   16, 0, 0);
}

// ---- dtype detector ----
__global__ void detect_mode(const unsigned short* __restrict__ w, int* __restrict__ flags) {
  int t = threadIdx.x;
  int trips = 0;
  for (int i = 0; i < 4; i++) {
    unsigned short u = w[t * 4 + i];
    int e = (u >> 7) & 0xFF;
    if (e >= 161 || (e <= 93 && e != 0)) trips++;
  }
  for (int off = 32; off > 0; off >>= 1) trips += __shfl_down(trips, off);
  if (t == 0) flags[0] = (trips >= 8) ? 1 : 0;  // 1 = fp32 I/O, 0 = bf16
}

// ---- X -> bf16 ----
__global__ __launch_bounds__(256) void convert_x(const void* __restrict__ xin,
                                                 unsigned short* __restrict__ xb,
                                                 const int* __restrict__ flags, int n) {
  int mode = flags[0];
  int i = (blockIdx.x * 256 + threadIdx.x) * 8;
  if (i >= n) return;
  if (mode) {
    const float* f = (const float*)xin;
    us8 o;
#pragma unroll
    for (int j = 0; j < 8; j++) o[j] = f2b(f[i + j]);
    *(us8*)&xb[i] = o;
  } else {
    *(us8*)&xb[i] = *(const us8*)((const unsigned short*)xin + i);
  }
}

// ---- W [R][C] -> bf16 W^T [C][R] ----
__global__ __launch_bounds__(256) void transpose_w(const void* __restrict__ win,
                                                   unsigned short* __restrict__ out,
                                                   const int* __restrict__ flags,
                                                   int R, int C) {
  __shared__ float tile[32][33];
  int mode = flags[0];
  int c0 = blockIdx.x * 32, r0 = blockIdx.y * 32;
  int tx = threadIdx.x & 31, ty = threadIdx.x >> 5;
  if (mode) {
    const float* f = (const float*)win;
    for (int i = ty; i < 32; i += 8) tile[i][tx] = f[(size_t)(r0 + i) * C + c0 + tx];
  } else {
    const unsigned short* bsrc = (const unsigned short*)win;
    for (int i = ty; i < 32; i += 8) tile[i][tx] = b2f(bsrc[(size_t)(r0 + i) * C + c0 + tx]);
  }
  __syncthreads();
  for (int i = ty; i < 32; i += 8) out[(size_t)(c0 + i) * R + r0 + tx] = f2b(tile[tx][i]);
}

#define QSC 0.18033688011112042f   // (1/8) * log2(e)

// ---- fused QKV GEMM + RoPE + head-major scatter ----
// BK=64 as two 128x32 LDS panels (row stride 64B -> no bank-conflict pile-up).
// V is written directly transposed: vt[b][vh][d][s].
__global__ __launch_bounds__(256)
void gemm_qkv(const unsigned short* __restrict__ A, const unsigned short* __restrict__ Bt,
              const int* __restrict__ pos_ids,
              unsigned short* __restrict__ qws, unsigned short* __restrict__ kws,
              unsigned short* __restrict__ vt) {
  __shared__ __align__(16) unsigned short lA[2 * 128 * 32];
  __shared__ __align__(16) unsigned short lB[2 * 128 * 32];
  int tid = threadIdx.x, lane = tid & 63, wave = tid >> 6;
  int wm = wave >> 1, wn = wave & 1;
  int quad = lane >> 4, l15 = lane & 15;
  size_t tm0 = (size_t)blockIdx.y * 128, tn0 = (size_t)blockIdx.x * 128;

  f32x4 zero4 = {0.f, 0.f, 0.f, 0.f};
  f32x4 acc[4][4];
#pragma unroll
  for (int mi = 0; mi < 4; mi++)
#pragma unroll
    for (int ni = 0; ni < 4; ni++) acc[mi][ni] = zero4;

  for (int kt = 0; kt < 32; kt++) {
    __syncthreads();
#pragma unroll
    for (int i = 0; i < 4; i++) {
      int c = tid + 256 * i;              // 0..1023; lds off = c*16B (lane-contiguous)
      int col = (c & 3) * 8;
      int r = (c >> 2) & 127;
      int half = c >> 9;
      async_copy16(&lA[c * 8], A + (tm0 + r) * DH + kt * 64 + half * 32 + col);
      async_copy16(&lB[c * 8], Bt + (tn0 + r) * DH + kt * 64 + half * 32 + col);
    }
    __syncthreads();
#pragma unroll
    for (int ks = 0; ks < 2; ks++) {
      bf16x8 af[4], bfr[4];
#pragma unroll
      for (int mi = 0; mi < 4; mi++)
        af[mi] = *(const bf16x8*)&lA[ks * 4096 + (wm * 64 + mi * 16 + l15) * 32 + quad * 8];
#pragma unroll
      for (int ni = 0; ni < 4; ni++)
        bfr[ni] = *(const bf16x8*)&lB[ks * 4096 + (wn * 64 + ni * 16 + l15) * 32 + quad * 8];
#pragma unroll
      for (int mi = 0; mi < 4; mi++)
#pragma unroll
        for (int ni = 0; ni < 4; ni++)
          acc[mi][ni] = __builtin_amdgcn_mfma_f32_16x16x32_bf16(af[mi], bfr[ni], acc[mi][ni], 0, 0, 0);
    }
  }

  int hs = (int)(tn0 >> 6) + wn;  // head slot 0..47 (wave-uniform)
  if (hs < 40) {
    float sc = (hs < 32) ? QSC : 1.0f;
    unsigned short* dst0 = (hs < 32) ? qws : kws;
    int hh = (hs < 32) ? hs : (hs - 32);
    float invf0 = __expf(-(float)l15 * (9.210340371976184f / 32.0f));
    float invf1 = invf0 * 0.01f;
#pragma unroll
    for (int mi = 0; mi < 4; mi++)
#pragma unroll
      for (int r = 0; r < 4; r++) {
        size_t gr = tm0 + wm * 64 + mi * 16 + quad * 4 + r;
        int b = (int)(gr >> 11), s = (int)(gr & 2047);
        float t = (float)pos_ids[gr];
        unsigned short* row = dst0 + ((size_t)(b * ((hs < 32) ? DNH : DKVH) + hh) * DS + s) * DHD;
#pragma unroll
        for (int ni = 0; ni < 2; ni++) {
          float x1 = acc[mi][ni][r], x2 = acc[mi][ni + 2][r];
          float ang = t * (ni ? invf1 : invf0);
          float sn, cs;
          __sincosf(ang, &sn, &cs);
          int d = ni * 16 + l15;
          row[d]      = f2b((x1 * cs - x2 * sn) * sc);
          row[d + 32] = f2b((x2 * cs + x1 * sn) * sc);
        }
      }
  } else {
    // V -> transposed vt[b][vh][d][s]; lane holds 4 consecutive s for fixed d
    int vh = hs - 40;
    int b = (int)(tm0 >> 11);
    int s0 = (int)(tm0 & 2047) + wm * 64 + quad * 4;
#pragma unroll
    for (int mi = 0; mi < 4; mi++)
#pragma unroll
      for (int ni = 0; ni < 4; ni++) {
        int d = ni * 16 + l15;
        us4 o4;
#pragma unroll
        for (int r = 0; r < 4; r++) o4[r] = f2b(acc[mi][ni][r]);
        *(us4*)&vt[((size_t)(b * DKVH + vh) * DHD + d) * DS + s0 + mi * 16] = o4;
      }
  }
}

// ---- out GEMM: d_out[M,N] = ctx * Wo^T (BK=64, split panels) ----
__global__ __launch_bounds__(256)
void gemm_out(const unsigned short* __restrict__ A, const unsigned short* __restrict__ Bt,
              unsigned short* __restrict__ Cb, float* __restrict__ Cf,
              const int* __restrict__ outmode) {
  __shared__ __align__(16) unsigned short lA[2 * 128 * 32];
  __shared__ __align__(16) unsigned short lB[2 * 128 * 32];
  int tid = threadIdx.x, lane = tid & 63, wave = tid >> 6;
  int wm = wave >> 1, wn = wave & 1;
  int quad = lane >> 4, l15 = lane & 15;
  size_t tm0 = (size_t)blockIdx.y * 128, tn0 = (size_t)blockIdx.x * 128;

  f32x4 zero4 = {0.f, 0.f, 0.f, 0.f};
  f32x4 acc[4][4];
#pragma unroll
  for (int mi = 0; mi < 4; mi++)
#pragma unroll
    for (int ni = 0; ni < 4; ni++) acc[mi][ni] = zero4;

  for (int kt = 0; kt < 32; kt++) {
    __syncthreads();
#pragma unroll
    for (int i = 0; i < 4; i++) {
      int c = tid + 256 * i;
      int col = (c & 3) * 8;
      int r = (c >> 2) & 127;
      int half = c >> 9;
      async_copy16(&lA[c * 8], A + (tm0 + r) * DH + kt * 64 + half * 32 + col);
      async_copy16(&lB[c * 8], Bt + (tn0 + r) * DH + kt * 64 + half * 32 + col);
    }
    __syncthreads();
#pragma unroll
    for (int ks = 0; ks < 2; ks++) {
      bf16x8 af[4], bfr[4];
#pragma unroll
      for (int mi = 0; mi < 4; mi++)
        af[mi] = *(const bf16x8*)&lA[ks * 4096 + (wm * 64 + mi * 16 + l15) * 32 + quad * 8];
#pragma unroll
      for (int ni = 0; ni < 4; ni++)
        bfr[ni] = *(const bf16x8*)&lB[ks * 4096 + (wn * 64 + ni * 16 + l15) * 32 + quad * 8];
#pragma unroll
      for (int mi = 0; mi < 4; mi++)
#pragma unroll
        for (int ni = 0; ni < 4; ni++)
          acc[mi][ni] = __builtin_amdgcn_mfma_f32_16x16x32_bf16(af[mi], bfr[ni], acc[mi][ni], 0, 0, 0);
    }
  }
  int mode = *outmode;
#pragma unroll
  for (int mi = 0; mi < 4; mi++)
#pragma unroll
    for (int ni = 0; ni < 4; ni++)
#pragma unroll
      for (int r = 0; r < 4; r++) {
        size_t gr = tm0 + wm * 64 + mi * 16 + quad * 4 + r;
        size_t gc = tn0 + wn * 64 + ni * 16 + l15;
        float v = acc[mi][ni][r];
        if (mode) Cf[gr * DH + gc] = v;
        else      Cb[gr * DH + gc] = f2b(v);
      }
}

// ---- causal GQA flash attention (S^T form, paired q-tiles) ----
__global__ __launch_bounds__(256, 4)
void flash_attn(const unsigned short* __restrict__ q, const unsigned short* __restrict__ k,
                const unsigned short* __restrict__ vt, unsigned short* __restrict__ ctx) {
  __shared__ __align__(16) unsigned short lK0[64 * 32];
  __shared__ __align__(16) unsigned short lK1[64 * 32];
  __shared__ __align__(16) unsigned short lV0[64 * 32];
  __shared__ __align__(16) unsigned short lV1[64 * 32];
  __shared__ __align__(16) unsigned short lP[4 * 16 * 72];
  int tid = threadIdx.x, lane = tid & 63, wave = tid >> 6;
  int quad = lane >> 4, l15 = lane & 15;
  int bh = blockIdx.y, b = bh >> 5, h = bh & 31, kvh = h >> 2;
  const unsigned short* qb = q + (size_t)(b * DNH + h) * DS * DHD;
  const unsigned short* kb = k + (size_t)(b * DKVH + kvh) * DS * DHD;
  const unsigned short* vb = vt + (size_t)(b * DKVH + kvh) * DHD * DS;
  unsigned short* lPw = lP + wave * 16 * 72;
  int r4 = tid >> 2, c8 = (tid & 3) * 8;

  f32x4 zero4 = {0.f, 0.f, 0.f, 0.f};
  for (int ph = 0; ph < 2; ph++) {
    int qt = ph ? (31 - blockIdx.x) : blockIdx.x;
    int q0 = qt * 64;
    const unsigned short* qp = qb + (size_t)(q0 + wave * 16 + l15) * DHD + quad * 8;
    bf16x8 qf0 = *(const bf16x8*)qp;
    bf16x8 qf1 = *(const bf16x8*)(qp + 32);
    f32x4 oacc[4];
#pragma unroll
    for (int dj = 0; dj < 4; dj++) oacc[dj] = zero4;
    float mrow = -1e30f, lrow = 0.f;

    int nt = qt + 1;
    for (int t = 0; t < nt; t++) {
      int kv0 = t * 64;
      __syncthreads();
      async_copy16(&lK0[tid * 8], kb + (size_t)(kv0 + r4) * DHD + c8);
      async_copy16(&lK1[tid * 8], kb + (size_t)(kv0 + r4) * DHD + 32 + c8);
      async_copy16(&lV0[tid * 8], vb + (size_t)r4 * DS + kv0 + c8);
      async_copy16(&lV1[tid * 8], vb + (size_t)r4 * DS + kv0 + 32 + c8);
      __syncthreads();

      f32x4 sacc[4];
#pragma unroll
      for (int nj = 0; nj < 4; nj++) {
        sacc[nj] = zero4;
        bf16x8 kf0 = *(const bf16x8*)&lK0[(nj * 16 + l15) * 32 + quad * 8];
        bf16x8 kf1 = *(const bf16x8*)&lK1[(nj * 16 + l15) * 32 + quad * 8];
        sacc[nj] = __builtin_amdgcn_mfma_f32_16x16x32_bf16(kf0, qf0, sacc[nj], 0, 0, 0);
        sacc[nj] = __builtin_amdgcn_mfma_f32_16x16x32_bf16(kf1, qf1, sacc[nj], 0, 0, 0);
      }
      if (t == nt - 1) {
        int ql = wave * 16 + l15;
#pragma unroll
        for (int nj = 0; nj < 4; nj++)
#pragma unroll
          for (int r = 0; r < 4; r++)
            if (nj * 16 + quad * 4 + r > ql) sacc[nj][r] = -1e30f;
      }
      float tm = -1e30f;
#pragma unroll
      for (int nj = 0; nj < 4; nj++)
#pragma unroll
        for (int r = 0; r < 4; r++) tm = fmaxf(tm, sacc[nj][r]);
      tm = fmaxf(tm, __shfl_xor(tm, 16));
      tm = fmaxf(tm, __shfl_xor(tm, 32));
      float mn = fmaxf(mrow, tm);
      float alpha = __builtin_amdgcn_exp2f(mrow - mn);
      mrow = mn;
      float rs = 0.f;
      float p[4][4];
#pragma unroll
      for (int nj = 0; nj < 4; nj++)
#pragma unroll
        for (int r = 0; r < 4; r++) {
          float e = __builtin_amdgcn_exp2f(sacc[nj][r] - mn);
          p[nj][r] = e;
          rs += e;
        }
      rs += __shfl_xor(rs, 16);
      rs += __shfl_xor(rs, 32);
      lrow = lrow * alpha + rs;
#pragma unroll
      for (int nj = 0; nj < 4; nj++) {
        us4 w4;
#pragma unroll
        for (int r = 0; r < 4; r++) w4[r] = f2b(p[nj][r]);
        *(us4*)&lPw[l15 * 72 + nj * 16 + quad * 4] = w4;
      }
      bf16x8 pf0 = *(const bf16x8*)&lPw[l15 * 72 + quad * 8];
      bf16x8 pf1 = *(const bf16x8*)&lPw[l15 * 72 + 32 + quad * 8];
#pragma unroll
      for (int dj = 0; dj < 4; dj++) {
#pragma unroll
        for (int r = 0; r < 4; r++) oacc[dj][r] *= alpha;
        bf16x8 vf0 = *(const bf16x8*)&lV0[(dj * 16 + l15) * 32 + quad * 8];
        bf16x8 vf1 = *(const bf16x8*)&lV1[(dj * 16 + l15) * 32 + quad * 8];
        oacc[dj] = __builtin_amdgcn_mfma_f32_16x16x32_bf16(vf0, pf0, oacc[dj], 0, 0, 0);
        oacc[dj] = __builtin_amdgcn_mfma_f32_16x16x32_bf16(vf1, pf1, oacc[dj], 0, 0, 0);
      }
    }
    float inv = __builtin_amdgcn_rcpf(lrow);
    size_t orow = ((size_t)b * DS + q0 + wave * 16 + l15) * (DNH * DHD) + (size_t)h * DHD;
#pragma unroll
    for (int dj = 0; dj < 4; dj++) {
      us4 o4;
#pragma unroll
      for (int r = 0; r < 4; r++) o4[r] = f2b(oacc[dj][r] * inv);
      *(us4*)&ctx[orow + dj * 16 + quad * 4] = o4;
    }
  }
}

extern "C" void kernel_launch(void* const* d_in, const int* in_sizes, int n_in,
                              void* d_out, int out_size, void* d_ws, size_t ws_size,
                              hipStream_t stream) {
  (void)in_sizes; (void)n_in; (void)out_size; (void)ws_size;
  const void* hs = d_in[0];
  const int* pos = (const int*)d_in[2];
  const void* wq = d_in[3];
  const void* wk = d_in[4];
  const void* wv = d_in[5];
  const void* wo = d_in[6];

  char* ws = (char*)d_ws;
  size_t off = 0;
  auto take = [&](size_t bytes) -> char* {
    char* p = ws + off;
    off += (bytes + 255) & ~(size_t)255;
    return p;
  };
  int* flags            = (int*)take(256);
  unsigned short* xb    = (unsigned short*)take((size_t)DM * DH * 2);
  unsigned short* wtqkv = (unsigned short*)take((size_t)DNQKV * DH * 2);
  unsigned short* wto   = (unsigned short*)take((size_t)DH * DH * 2);
  unsigned short* qws   = (unsigned short*)take((size_t)DB * DNH * DS * DHD * 2);
  unsigned short* kws   = (unsigned short*)take((size_t)DB * DKVH * DS * DHD * 2);
  unsigned short* vtws  = (unsigned short*)take((size_t)DB * DKVH * DS * DHD * 2);
  unsigned short* ctx   = (unsigned short*)take((size_t)DM * DNH * DHD * 2);

  detect_mode<<<1, 64, 0, stream>>>((const unsigned short*)wq, flags);
  convert_x<<<DM * DH / 8 / 256, 256, 0, stream>>>(hs, xb, flags, DM * DH);
  transpose_w<<<dim3(64, 64), 256, 0, stream>>>(wq, wtqkv, flags, 2048, 2048);
  transpose_w<<<dim3(16, 64), 256, 0, stream>>>(wk, wtqkv + (size_t)2048 * 2048, flags, 2048, 512);
  transpose_w<<<dim3(16, 64), 256, 0, stream>>>(wv, wtqkv + (size_t)2560 * 2048, flags, 2048, 512);
  transpose_w<<<dim3(64, 64), 256, 0, stream>>>(wo, wto, flags, 2048, 2048);

  gemm_qkv<<<dim3(24, 32), 256, 0, stream>>>(xb, wtqkv, pos, qws, kws, vtws);

  flash_attn<<<dim3(16, DB * DNH), 256, 0, stream>>>(qws, kws, vtws, ctx);

  gemm_out<<<dim3(16, 32), 256, 0, stream>>>(ctx, wto, (unsigned short*)d_out, (float*)d_out, flags);
}